// Round 1
// 240.667 us; speedup vs baseline: 1.0110x; 1.0110x over previous
//
#include <hip/hip_runtime.h>
#include <hip/hip_bf16.h>

// ---------------- problem constants ----------------
// B=2 T2=9 T3=27 T1=243 P=17 K2=9 C=128
// CH = {48,96,192,384}, HW = {(96,72),(48,36),(24,18),(12,9)}, N=18
static constexpr int NQ_SIZE = 9517824;
static constexpr int NV_SIZE = 1057536;
static constexpr int NPOS    = 74358;   // 486*153 sampling points
static constexpr int M_CONV  = 8262;    // 2*243*17 rows of the conv GEMM

// E-map (projected feature, bf16, channels-last [n,h,w,128]) element offsets in ws
static constexpr long E0_OFF = 0;
static constexpr long E1_OFF = 15925248;            // 18*96*72*128
static constexpr long E2_OFF = E1_OFF + 3981312;    // 18*48*36*128
static constexpr long E3_OFF = E2_OFF + 995328;     // 18*24*18*128
static constexpr long E_END  = E3_OFF + 248832;     // 18*12*9*128  -> 21,150,720 elems

// prep kernel block-range segmentation (long-serial levels first, sampos early)
static constexpr int SEG_L3 = 18;             // M=108  K=384, 1 tile  x 18
static constexpr int SEG_SP = SEG_L3 + 486;   // sampling positions (latency-bound, start early)
static constexpr int SEG_L2 = SEG_SP + 72;    // M=432  K=192, 4 tiles x 18
static constexpr int SEG_L1 = SEG_L2 + 252;   // M=1728 K=96, 14 tiles x 18
static constexpr int SEG_L0 = SEG_L1 + 972;   // M=6912 K=48, 54 tiles x 18 (no masking!)
static constexpr int SEG_CT = SEG_L0 + 576;   // convT2: 147456/256 (trivial, last)
static constexpr int PREP_GRID = SEG_CT;      // 2376

typedef __attribute__((ext_vector_type(8))) short short8;   // 8 bf16 (4 VGPRs)
typedef __attribute__((ext_vector_type(4))) float floatx4;

__device__ __forceinline__ float bf2f(unsigned short u) {
    union { unsigned int i; float f; } v; v.i = ((unsigned)u) << 16; return v.f;
}
__device__ __forceinline__ unsigned short f2bf_rne(float f) {
    union { float f; unsigned int i; } v; v.f = f;
    unsigned int u = v.i;
    u += 0x7fffu + ((u >> 16) & 1u);
    return (unsigned short)(u >> 16);
}
__device__ __forceinline__ short8 pack8(const float* t) {
    union { unsigned short u[8]; short8 s; } r;
    #pragma unroll
    for (int i = 0; i < 8; ++i) r.u[i] = f2bf_rne(t[i]);
    return r.s;
}

// ---------------- projection GEMM body ----------------
// E[m, o] = sum_k A[k, m] * W[o, k]   (A = f_l slab, column-major in m; W = we_l)
// Tile M=128 x N=128 per block, 4 waves each owning 32 rows (2 A-frags).
// B staged to LDS once per <=96-wide K-chunk (zero-padded to mult of 32),
// then a BARRIER-FREE k-loop: A direct global->reg, B ds_read_b128, 16 MFMA
// per wave per 32-k step. Barriers: 1 (K<=96), 3 (K=192), 7 (K=384).
template<int K, int M, bool FULLM>
__device__ __forceinline__ void proj_body(
    const float* __restrict__ A, const float* __restrict__ W,
    unsigned short* __restrict__ Eo, int m0, int tid,
    unsigned short (*Bs)[104])
{
    constexpr int KC      = (K < 96) ? K : 96;     // chunk width
    constexpr int KCPAD   = (KC + 31) & ~31;       // padded to mult of 32
    constexpr int KT      = KCPAD / 32;            // k-tiles per chunk
    constexpr int NCH     = K / KC;                // chunks
    constexpr bool NEEDPAD = (KCPAD != KC);        // only K=48

    const int lane = tid & 63;
    const int wave = tid >> 6;
    const int l15  = lane & 15;
    const int quad = lane >> 4;
    const int mg0  = m0 + wave * 32 + l15;
    const int mg1  = mg0 + 16;
    const bool v0  = FULLM || (mg0 < M);
    const bool v1  = FULLM || (mg1 < M);

    floatx4 acc[2][8];
    #pragma unroll
    for (int f = 0; f < 2; ++f)
        #pragma unroll
        for (int nt = 0; nt < 8; ++nt) acc[f][nt] = (floatx4){0.f, 0.f, 0.f, 0.f};

    // B staging split: thread -> o = tid>>1 (0..127), k-half = (tid&1)*KCPAD/2
    const int so  = tid >> 1;
    const int skb = (tid & 1) * (KCPAD / 2);

    #pragma unroll 1
    for (int ch = 0; ch < NCH; ++ch) {
        const int kc = ch * KC;
        if (ch) __syncthreads();     // protect Bs before overwrite
        // ---- stage B chunk (fp32 global -> bf16 LDS), zero-pad beyond KC ----
        {
            const float* wp = W + (long)so * K + kc + skb;
            #pragma unroll
            for (int k = 0; k < KCPAD / 2; k += 8) {
                float t[8];
                #pragma unroll
                for (int j = 0; j < 8; ++j)
                    t[j] = (!NEEDPAD || (skb + k + j < KC)) ? wp[k + j] : 0.f;
                unsigned short u[8];
                #pragma unroll
                for (int j = 0; j < 8; ++j) u[j] = f2bf_rne(t[j]);
                *(uint4*)&Bs[so][skb + k] = *(const uint4*)u;
            }
        }
        __syncthreads();

        // ---- barrier-free k-loop over this chunk ----
        #pragma unroll
        for (int kt = 0; kt < KT; ++kt) {
            const int kg = kc + kt * 32 + quad * 8;   // global k of first A elem
            float a0[8], a1[8];
            const float* ap = A + (long)kg * M + mg0;
            const bool fastk = !NEEDPAD || (kg + 8 <= K);
            if (FULLM && fastk) {
                #pragma unroll
                for (int j = 0; j < 8; ++j) {
                    a0[j] = ap[(long)j * M];
                    a1[j] = ap[(long)j * M + 16];
                }
            } else {
                #pragma unroll
                for (int j = 0; j < 8; ++j) {
                    a0[j] = 0.f; a1[j] = 0.f;
                    if (kg + j < K) {
                        if (v0) a0[j] = ap[(long)j * M];
                        if (v1) a1[j] = ap[(long)j * M + 16];
                    }
                }
            }
            short8 af0 = pack8(a0);
            short8 af1 = pack8(a1);
            #pragma unroll
            for (int nt = 0; nt < 8; ++nt) {
                short8 bf = *(const short8*)&Bs[nt * 16 + l15][kt * 32 + quad * 8];
                acc[0][nt] = __builtin_amdgcn_mfma_f32_16x16x32_bf16(af0, bf, acc[0][nt], 0, 0, 0);
                acc[1][nt] = __builtin_amdgcn_mfma_f32_16x16x32_bf16(af1, bf, acc[1][nt], 0, 0, 0);
            }
        }
    }

    // ---- epilogue: C/D col=lane&15 (o), row=quad*4+r within each 16-row frag ----
    #pragma unroll
    for (int f = 0; f < 2; ++f) {
        const int rb = m0 + wave * 32 + f * 16 + quad * 4;
        #pragma unroll
        for (int nt = 0; nt < 8; ++nt) {
            const int col = nt * 16 + l15;
            #pragma unroll
            for (int r = 0; r < 4; ++r) {
                if (FULLM || (rb + r < M))
                    Eo[(long)(rb + r) * 128 + col] = f2bf_rne(acc[f][nt][r]);
            }
        }
    }
}

// ---------------- fused prep kernel ----------------
__global__ __launch_bounds__(256) void prep_k(
    const float* __restrict__ f0, const float* __restrict__ f1,
    const float* __restrict__ f2, const float* __restrict__ f3,
    const float* __restrict__ we0, const float* __restrict__ we1,
    const float* __restrict__ we2, const float* __restrict__ we3,
    const float* __restrict__ conv_w, unsigned short* __restrict__ convT2,
    const float* __restrict__ query, const float* __restrict__ value,
    const float* __restrict__ key,
    const float* __restrict__ w_off, const float* __restrict__ b_off,
    const float* __restrict__ w_attn, const float* __restrict__ b_attn,
    float* __restrict__ samp, unsigned short* __restrict__ Ebase)
{
    const int bid = blockIdx.x;
    const int tid = threadIdx.x;

    if (bid < SEG_L3 || (bid >= SEG_SP && bid < SEG_L0)) {
        __shared__ unsigned short Bs[128][104];   // k-chunk <=96, pad->104 (16B rows, 2-way banks)

        if (bid < SEG_L3) {
            // L3: M=108, K=384, one masked tile per n
            int n = bid;
            proj_body<384, 108, false>(f3 + (long)n * 384 * 108, we3,
                Ebase + E3_OFF + (long)n * 108 * 128, 0, tid, Bs);
        } else if (bid < SEG_L2) {
            // L2: M=432, K=192, tiles of 128 (last masked: 48 rows)
            int r = bid - SEG_SP; int n = r >> 2, t = r & 3;
            const float* A = f2 + (long)n * 192 * 432;
            unsigned short* Eo = Ebase + E2_OFF + (long)n * 432 * 128;
            if (t < 3) proj_body<192, 432, true >(A, we2, Eo, t * 128, tid, Bs);
            else       proj_body<192, 432, false>(A, we2, Eo, t * 128, tid, Bs);
        } else if (bid < SEG_L1) {
            // L1: M=1728, K=96, tiles of 128 (last masked: 64 rows)
            int r = bid - SEG_L2; int n = r / 14, t = r - n * 14;
            const float* A = f1 + (long)n * 96 * 1728;
            unsigned short* Eo = Ebase + E1_OFF + (long)n * 1728 * 128;
            if (t < 13) proj_body<96, 1728, true >(A, we1, Eo, t * 128, tid, Bs);
            else        proj_body<96, 1728, false>(A, we1, Eo, t * 128, tid, Bs);
        } else {
            // L0: M=6912, K=48, 54 full tiles of 128 per n — fully unmasked path
            int r = bid - SEG_L1; int n = r / 54, t = r - n * 54;
            proj_body<48, 6912, true>(f0 + (long)n * 48 * 6912, we0,
                Ebase + E0_OFF + (long)n * 6912 * 128, t * 128, tid, Bs);
        }
    } else if (bid < SEG_SP) {
        // ---- sampling positions, one (b,t1) per block (placed early: latency-bound) ----
        const int bt1 = bid - SEG_L3;      // 0..485
        const int b  = bt1 / 243, t1 = bt1 - b * 243;
        const int t2 = t1 / 27,  t3 = t1 - t2 * 27;
        const int n  = b * 9 + t2;
        __shared__ float logit[17][2];
        __shared__ float aw[17][2];

        if (tid < 34) {
            int p = tid >> 1, o = tid & 1;
            const float* vrow = value + ((long)bt1 * 17 + p) * 128;
            const float* wrow = w_attn + o * 128;
            float s = 0.f;
            for (int c = 0; c < 128; c += 4) {
                float4 v = *(const float4*)(vrow + c);
                float4 w = *(const float4*)(wrow + c);
                s += v.x * w.x + v.y * w.y + v.z * w.z + v.w * w.w;
            }
            logit[p][o] = s + b_attn[o];
        }
        __syncthreads();
        if (tid < 17) {
            float l0 = logit[tid][0], l1 = logit[tid][1];
            float mx = fmaxf(l0, l1);
            float e0 = expf(l0 - mx), e1 = expf(l1 - mx);
            float inv = 1.f / (e0 + e1);
            aw[tid][0] = e0 * inv; aw[tid][1] = e1 * inv;
        }
        __syncthreads();
        for (int j = tid; j < 306; j += 256) {
            int q = j >> 1, o = j & 1;
            const float* qrow = query + ((long)bt1 * 153 + q) * 128;
            const float* wrow = w_off + o * 128;
            float s = 0.f;
            for (int c = 0; c < 128; c += 4) {
                float4 v = *(const float4*)(qrow + c);
                float4 w = *(const float4*)(wrow + c);
                s += v.x * w.x + v.y * w.y + v.z * w.z + v.w * w.w;
            }
            float off = tanhf(s + b_off[o]);
            float sp = off * aw[q % 17][o];
            long kidx = (((long)n * 27 + t3) * 153 + q) * 2 + o;
            samp[kidx] = key[kidx] + sp;
        }
    } else {
        // ---- convT2 transpose+cast (trivial, last) ----
        int idx = (bid - SEG_L0) * 256 + tid;
        if (idx < 147456) {
            int o = idx / 1152, kk = idx - o * 1152;
            int k2 = kk >> 7, c = kk & 127;
            convT2[idx] = f2bf_rne(conv_w[o * 1152 + c * 9 + k2]);
        }
    }
}

// ---------------- gather + mean + blend -> new_query ----------------
// 8 positions/block, 32 lanes/position, 4 channels/lane (float4).
__global__ __launch_bounds__(256) void gather_k(
    const unsigned short* __restrict__ Ebase,
    const float* __restrict__ samp, const float* __restrict__ query,
    const float* __restrict__ be0, const float* __restrict__ be1,
    const float* __restrict__ be2, const float* __restrict__ be3,
    float* __restrict__ nq)
{
    const int tid = threadIdx.x;
    const int pos = blockIdx.x * 8 + (tid >> 5);
    if (pos >= NPOS) return;
    const int c4 = (tid & 31) << 2;
    const int bt1 = pos / 153, q = pos - bt1 * 153;
    const int b  = bt1 / 243, t1 = bt1 - b * 243;
    const int t2 = t1 / 27,  t3 = t1 - t2 * 27;
    const int n  = b * 9 + t2;
    const long sbase = (((long)n * 27 + t3) * 153 + q) * 2;
    const float gx = samp[sbase], gy = samp[sbase + 1];

    float ax = 0.f, ay = 0.f, az = 0.f, aww = 0.f;
    const long Eoffs[4] = {E0_OFF, E1_OFF, E2_OFF, E3_OFF};
    const int Hs[4] = {96, 48, 24, 12}, Wd[4] = {72, 36, 18, 9};
    #pragma unroll
    for (int l = 0; l < 4; ++l) {
        const int H = Hs[l], W = Wd[l];
        const unsigned short* E = Ebase + Eoffs[l] + (long)n * H * W * 128 + c4;
        float ix = ((gx + 1.f) * (float)W - 1.f) * 0.5f;
        float iy = ((gy + 1.f) * (float)H - 1.f) * 0.5f;
        float fx0 = floorf(ix), fy0 = floorf(iy);
        int x0 = (int)fx0, y0 = (int)fy0;
        int x1 = x0 + 1, y1 = y0 + 1;
        float wx1 = ix - fx0, wx0 = 1.f - wx1;
        float wy1 = iy - fy0, wy0 = 1.f - wy1;
        float w00 = wy0 * wx0, w01 = wy0 * wx1, w10 = wy1 * wx0, w11 = wy1 * wx1;
        bool vy0 = (unsigned)y0 < (unsigned)H, vy1 = (unsigned)y1 < (unsigned)H;
        bool vx0 = (unsigned)x0 < (unsigned)W, vx1 = (unsigned)x1 < (unsigned)W;
        if (vy0 && vx0) { ushort4 v = *(const ushort4*)(E + ((long)y0 * W + x0) * 128);
            ax = fmaf(w00, bf2f(v.x), ax); ay = fmaf(w00, bf2f(v.y), ay);
            az = fmaf(w00, bf2f(v.z), az); aww = fmaf(w00, bf2f(v.w), aww); }
        if (vy0 && vx1) { ushort4 v = *(const ushort4*)(E + ((long)y0 * W + x1) * 128);
            ax = fmaf(w01, bf2f(v.x), ax); ay = fmaf(w01, bf2f(v.y), ay);
            az = fmaf(w01, bf2f(v.z), az); aww = fmaf(w01, bf2f(v.w), aww); }
        if (vy1 && vx0) { ushort4 v = *(const ushort4*)(E + ((long)y1 * W + x0) * 128);
            ax = fmaf(w10, bf2f(v.x), ax); ay = fmaf(w10, bf2f(v.y), ay);
            az = fmaf(w10, bf2f(v.z), az); aww = fmaf(w10, bf2f(v.w), aww); }
        if (vy1 && vx1) { ushort4 v = *(const ushort4*)(E + ((long)y1 * W + x1) * 128);
            ax = fmaf(w11, bf2f(v.x), ax); ay = fmaf(w11, bf2f(v.y), ay);
            az = fmaf(w11, bf2f(v.z), az); aww = fmaf(w11, bf2f(v.w), aww); }
    }
    float bsx = be0[c4]     + be1[c4]     + be2[c4]     + be3[c4];
    float bsy = be0[c4 + 1] + be1[c4 + 1] + be2[c4 + 1] + be3[c4 + 1];
    float bsz = be0[c4 + 2] + be1[c4 + 2] + be2[c4 + 2] + be3[c4 + 2];
    float bsw = be0[c4 + 3] + be1[c4 + 3] + be2[c4 + 3] + be3[c4 + 3];
    float mx = 0.25f * (ax + bsx), my = 0.25f * (ay + bsy);
    float mz = 0.25f * (az + bsz), mw = 0.25f * (aww + bsw);
    const long qi = ((long)bt1 * 153 + q) * 128 + c4;
    float4 qv = *(const float4*)(query + qi);
    float4 o;
    o.x = 0.1f * mx + 0.9f * qv.x;
    o.y = 0.1f * my + 0.9f * qv.y;
    o.z = 0.1f * mz + 0.9f * qv.z;
    o.w = 0.1f * mw + 0.9f * qv.w;
    *(float4*)(nq + qi) = o;
}

// ---------------- conv GEMM via bf16 MFMA ----------------
// nv[m][o] = sum_kk nq[m*1152+kk] * convT2[o][kk] + conv_b[o]
__global__ __launch_bounds__(256) void conv_mfma_k(
    const float* __restrict__ nq, const unsigned short* __restrict__ convT2,
    const float* __restrict__ conv_b, float* __restrict__ nv)
{
    __shared__ unsigned short As[32][40];   // [m][k] pad 32->40
    __shared__ unsigned short Bs[64][40];   // [n][k]

    const int tid  = threadIdx.x;
    const int lane = tid & 63;
    const int wave = tid >> 6;
    const int wm = (wave & 1) * 16;
    const int wn = (wave >> 1) * 32;
    const int m0 = blockIdx.x * 32;
    const int n0 = blockIdx.y * 64;
    const int l15  = lane & 15;
    const int quad = lane >> 4;

    floatx4 acc[2];
    acc[0] = (floatx4){0.f, 0.f, 0.f, 0.f};
    acc[1] = acc[0];

    const int am = tid >> 3;             // 0..31
    const int ak = (tid & 7) << 2;       // 0,4,..,28
    const int bn = tid >> 2;             // 0..63
    const int bk = (tid & 3) << 3;       // 0,8,16,24

    float4 a0; uint4 bv;
    auto fetch = [&](int k0) {
        a0 = (float4){0,0,0,0};
        int row = m0 + am;
        if (row < M_CONV)
            a0 = *(const float4*)(nq + (long)row * 1152 + k0 + ak);
        bv = *(const uint4*)(convT2 + (long)(n0 + bn) * 1152 + k0 + bk);
    };
    fetch(0);

    for (int k0 = 0; k0 < 1152; k0 += 32) {
        unsigned short t[4] = {f2bf_rne(a0.x), f2bf_rne(a0.y), f2bf_rne(a0.z), f2bf_rne(a0.w)};
        *(uint2*)&As[am][ak] = *(const uint2*)t;
        *(uint4*)&Bs[bn][bk] = bv;
        __syncthreads();
        if (k0 + 32 < 1152) fetch(k0 + 32);

        short8 af = *(const short8*)&As[wm + l15][quad * 8];
        #pragma unroll
        for (int nt = 0; nt < 2; ++nt) {
            short8 bf = *(const short8*)&Bs[wn + nt * 16 + l15][quad * 8];
            acc[nt] = __builtin_amdgcn_mfma_f32_16x16x32_bf16(af, bf, acc[nt], 0, 0, 0);
        }
        __syncthreads();
    }

    #pragma unroll
    for (int nt = 0; nt < 2; ++nt) {
        int col = n0 + wn + nt * 16 + l15;
        float bias = conv_b[col];
        #pragma unroll
        for (int r = 0; r < 4; ++r) {
            int row = m0 + wm + quad * 4 + r;
            if (row < M_CONV)
                nv[(long)row * 128 + col] = acc[nt][r] + bias;
        }
    }
}

extern "C" void kernel_launch(void* const* d_in, const int* in_sizes, int n_in,
                              void* d_out, int out_size, void* d_ws, size_t ws_size,
                              hipStream_t stream) {
    const float* f0     = (const float*)d_in[0];
    const float* f1     = (const float*)d_in[1];
    const float* f2     = (const float*)d_in[2];
    const float* f3     = (const float*)d_in[3];
    const float* query  = (const float*)d_in[4];
    const float* key    = (const float*)d_in[5];
    const float* value  = (const float*)d_in[6];
    const float* w_off  = (const float*)d_in[7];
    const float* b_off  = (const float*)d_in[8];
    const float* w_attn = (const float*)d_in[9];
    const float* b_attn = (const float*)d_in[10];
    const float* we0    = (const float*)d_in[11];
    const float* be0    = (const float*)d_in[12];
    const float* we1    = (const float*)d_in[13];
    const float* be1    = (const float*)d_in[14];
    const float* we2    = (const float*)d_in[15];
    const float* be2    = (const float*)d_in[16];
    const float* we3    = (const float*)d_in[17];
    const float* be3    = (const float*)d_in[18];
    const float* conv_w = (const float*)d_in[19];
    const float* conv_b = (const float*)d_in[20];

    float* out  = (float*)d_out;
    float* nq   = out;                       // new_query
    float* nv   = out + NQ_SIZE;             // new_value
    float* samp = out + NQ_SIZE + NV_SIZE;   // sampling_positions

    // ws layout: E maps (bf16, 21,150,720) | convT2 (bf16, 147,456)
    unsigned short* Ebase  = (unsigned short*)d_ws;
    unsigned short* convT2 = Ebase + E_END;

    // 1. fused prep: projections (MFMA, stage-B-once, barrier-free k-loop)
    //    + sampling positions + convT2
    prep_k<<<PREP_GRID, 256, 0, stream>>>(
        f0, f1, f2, f3, we0, we1, we2, we3, conv_w, convT2,
        query, value, key, w_off, b_off, w_attn, b_attn, samp, Ebase);

    // 2. gather + mean + blend -> new_query (9295 blocks)
    gather_k<<<(NPOS + 7) / 8, 256, 0, stream>>>(Ebase, samp, query, be0, be1, be2, be3, nq);

    // 3. new_value GEMM via MFMA: M=8262, K=1152, N=128 (518 blocks)
    conv_mfma_k<<<dim3(259, 2), 256, 0, stream>>>(nq, convT2, conv_b, nv);
}

// Round 2
// 232.756 us; speedup vs baseline: 1.0454x; 1.0340x over previous
//
#include <hip/hip_runtime.h>
#include <hip/hip_bf16.h>

// ---------------- problem constants ----------------
// B=2 T2=9 T3=27 T1=243 P=17 K2=9 C=128
// CH = {48,96,192,384}, HW = {(96,72),(48,36),(24,18),(12,9)}, N=18
static constexpr int NQ_SIZE = 9517824;
static constexpr int NV_SIZE = 1057536;
static constexpr int NPOS    = 74358;   // 486*153 sampling points
static constexpr int M_CONV  = 8262;    // 2*243*17 rows of the conv GEMM

// E-map (projected feature, bf16, channels-last [n,h,w,128]) element offsets in ws
static constexpr long E0_OFF = 0;
static constexpr long E1_OFF = 15925248;            // 18*96*72*128
static constexpr long E2_OFF = E1_OFF + 3981312;    // 18*48*36*128
static constexpr long E3_OFF = E2_OFF + 995328;     // 18*24*18*128
static constexpr long E_END  = E3_OFF + 248832;     // 18*12*9*128  -> 21,150,720 elems

// prep kernel block-range segmentation
static constexpr int SEG_AW = 65;             // attention weights: 16524 threads
static constexpr int SEG_L3 = SEG_AW + 18;    // M=108  K=384, 1 tile  x 18
static constexpr int SEG_L2 = SEG_L3 + 72;    // M=432  K=192, 4 tiles x 18
static constexpr int SEG_L1 = SEG_L2 + 252;   // M=1728 K=96, 14 tiles x 18
static constexpr int SEG_L0 = SEG_L1 + 972;   // M=6912 K=48, 54 tiles x 18 (no masking)
static constexpr int SEG_CT = SEG_L0 + 576;   // convT2: 147456/256
static constexpr int PREP_GRID = SEG_CT;      // 1955

typedef __attribute__((ext_vector_type(8))) short short8;   // 8 bf16 (4 VGPRs)
typedef __attribute__((ext_vector_type(4))) float floatx4;

__device__ __forceinline__ float bf2f(unsigned short u) {
    union { unsigned int i; float f; } v; v.i = ((unsigned)u) << 16; return v.f;
}
__device__ __forceinline__ unsigned short f2bf_rne(float f) {
    union { float f; unsigned int i; } v; v.f = f;
    unsigned int u = v.i;
    u += 0x7fffu + ((u >> 16) & 1u);
    return (unsigned short)(u >> 16);
}
__device__ __forceinline__ short8 pack8(const float* t) {
    union { unsigned short u[8]; short8 s; } r;
    #pragma unroll
    for (int i = 0; i < 8; ++i) r.u[i] = f2bf_rne(t[i]);
    return r.s;
}

// ---------------- projection GEMM body ----------------
// E[m, o] = sum_k A[k, m] * W[o, k]   (A = f_l slab, column-major in m; W = we_l)
// Tile M=128 x N=128 per block, 4 waves each owning 32 rows (2 A-frags).
// Per K-chunk (<=96): issue B global loads, then ALL A k-tile loads (regs),
// THEN convert+stage B and barrier — A latency hides under stage+barrier.
template<int K, int M, bool FULLM>
__device__ __forceinline__ void proj_body(
    const float* __restrict__ A, const float* __restrict__ W,
    unsigned short* __restrict__ Eo, int m0, int tid,
    unsigned short (*Bs)[104])
{
    constexpr int KC      = (K < 96) ? K : 96;     // chunk width
    constexpr int KCPAD   = (KC + 31) & ~31;       // padded to mult of 32
    constexpr int KT      = KCPAD / 32;            // k-tiles per chunk
    constexpr int NCH     = K / KC;                // chunks
    constexpr bool NEEDPAD = (KCPAD != KC);        // only K=48

    const int lane = tid & 63;
    const int wave = tid >> 6;
    const int l15  = lane & 15;
    const int quad = lane >> 4;
    const int mg0  = m0 + wave * 32 + l15;
    const int mg1  = mg0 + 16;
    const bool v0  = FULLM || (mg0 < M);
    const bool v1  = FULLM || (mg1 < M);

    floatx4 acc[2][8];
    #pragma unroll
    for (int f = 0; f < 2; ++f)
        #pragma unroll
        for (int nt = 0; nt < 8; ++nt) acc[f][nt] = (floatx4){0.f, 0.f, 0.f, 0.f};

    // B staging split: thread -> o = tid>>1 (0..127), k-half = (tid&1)*KCPAD/2
    const int so  = tid >> 1;
    const int skb = (tid & 1) * (KCPAD / 2);

    #pragma unroll 1
    for (int ch = 0; ch < NCH; ++ch) {
        const int kc = ch * KC;

        // ---- 1. issue B global loads (regs) ----
        float bt[KCPAD / 2];
        {
            const float* wp = W + (long)so * K + kc + skb;
            #pragma unroll
            for (int j = 0; j < KCPAD / 2; ++j) {
                bt[j] = 0.f;
                if (!NEEDPAD || (skb + j < KC)) bt[j] = wp[j];
            }
        }

        // ---- 2. issue ALL A k-tile loads for this chunk (regs) ----
        float a0[KT][8], a1[KT][8];
        #pragma unroll
        for (int kt = 0; kt < KT; ++kt) {
            const int kg = kc + kt * 32 + quad * 8;
            const float* ap = A + (long)kg * M + mg0;
            if (FULLM && (!NEEDPAD || (kg + 8 <= K))) {
                #pragma unroll
                for (int j = 0; j < 8; ++j) {
                    a0[kt][j] = ap[(long)j * M];
                    a1[kt][j] = ap[(long)j * M + 16];
                }
            } else {
                #pragma unroll
                for (int j = 0; j < 8; ++j) {
                    a0[kt][j] = 0.f; a1[kt][j] = 0.f;
                    if (kg + j < K) {
                        if (v0) a0[kt][j] = ap[(long)j * M];
                        if (v1) a1[kt][j] = ap[(long)j * M + 16];
                    }
                }
            }
        }

        // ---- 3. stage B to LDS (bf16) ----
        if (ch) __syncthreads();   // previous chunk's readers done
        {
            #pragma unroll
            for (int j = 0; j < KCPAD / 2; j += 8) {
                unsigned short u[8];
                #pragma unroll
                for (int i = 0; i < 8; ++i) u[i] = f2bf_rne(bt[j + i]);
                *(uint4*)&Bs[so][skb + j] = *(const uint4*)u;
            }
        }
        __syncthreads();

        // ---- 4. MFMA over this chunk ----
        #pragma unroll
        for (int kt = 0; kt < KT; ++kt) {
            short8 af0 = pack8(a0[kt]);
            short8 af1 = pack8(a1[kt]);
            #pragma unroll
            for (int nt = 0; nt < 8; ++nt) {
                short8 bf = *(const short8*)&Bs[nt * 16 + l15][kt * 32 + quad * 8];
                acc[0][nt] = __builtin_amdgcn_mfma_f32_16x16x32_bf16(af0, bf, acc[0][nt], 0, 0, 0);
                acc[1][nt] = __builtin_amdgcn_mfma_f32_16x16x32_bf16(af1, bf, acc[1][nt], 0, 0, 0);
            }
        }
    }

    // ---- epilogue: C/D col=lane&15 (o), row=quad*4+r within each 16-row frag ----
    #pragma unroll
    for (int f = 0; f < 2; ++f) {
        const int rb = m0 + wave * 32 + f * 16 + quad * 4;
        #pragma unroll
        for (int nt = 0; nt < 8; ++nt) {
            const int col = nt * 16 + l15;
            #pragma unroll
            for (int r = 0; r < 4; ++r) {
                if (FULLM || (rb + r < M))
                    Eo[(long)(rb + r) * 128 + col] = f2bf_rne(acc[f][nt][r]);
            }
        }
    }
}

// ---------------- fused prep kernel ----------------
// AW segment: aw[bt1][p][o] = softmax_o(value[bt1,p]·w_attn[o] + b_attn[o])
// proj segments: E-map projections (MFMA)
// CT segment: convT2 transpose+cast
__global__ __launch_bounds__(256) void prep_k(
    const float* __restrict__ f0, const float* __restrict__ f1,
    const float* __restrict__ f2, const float* __restrict__ f3,
    const float* __restrict__ we0, const float* __restrict__ we1,
    const float* __restrict__ we2, const float* __restrict__ we3,
    const float* __restrict__ conv_w, unsigned short* __restrict__ convT2,
    const float* __restrict__ value,
    const float* __restrict__ w_attn, const float* __restrict__ b_attn,
    float* __restrict__ awbuf, unsigned short* __restrict__ Ebase)
{
    const int bid = blockIdx.x;
    const int tid = threadIdx.x;

    if (bid < SEG_AW) {
        // ---- attention weights: 2 threads per (bt1,p) row, shfl partner swap ----
        int t = bid * 256 + tid;
        if (t < 16524) {
            int rp = t >> 1, o = t & 1;
            const float* vrow = value + (long)rp * 128;
            const float* wrow = w_attn + o * 128;
            float s = 0.f;
            for (int c = 0; c < 128; c += 4) {
                float4 v = *(const float4*)(vrow + c);
                float4 w = *(const float4*)(wrow + c);
                s += v.x * w.x + v.y * w.y + v.z * w.z + v.w * w.w;
            }
            s += b_attn[o];
            float so = __shfl_xor(s, 1);
            float m = fmaxf(s, so);
            float e = __expf(s - m), eo = __expf(so - m);
            awbuf[t] = e / (e + eo);
        }
    } else if (bid < SEG_L0) {
        __shared__ unsigned short Bs[128][104];   // k-chunk <=96, pad->104

        if (bid < SEG_L3) {
            int n = bid - SEG_AW;
            proj_body<384, 108, false>(f3 + (long)n * 384 * 108, we3,
                Ebase + E3_OFF + (long)n * 108 * 128, 0, tid, Bs);
        } else if (bid < SEG_L2) {
            int r = bid - SEG_L3; int n = r >> 2, t = r & 3;
            const float* A = f2 + (long)n * 192 * 432;
            unsigned short* Eo = Ebase + E2_OFF + (long)n * 432 * 128;
            if (t < 3) proj_body<192, 432, true >(A, we2, Eo, t * 128, tid, Bs);
            else       proj_body<192, 432, false>(A, we2, Eo, t * 128, tid, Bs);
        } else if (bid < SEG_L1) {
            int r = bid - SEG_L2; int n = r / 14, t = r - n * 14;
            const float* A = f1 + (long)n * 96 * 1728;
            unsigned short* Eo = Ebase + E1_OFF + (long)n * 1728 * 128;
            if (t < 13) proj_body<96, 1728, true >(A, we1, Eo, t * 128, tid, Bs);
            else        proj_body<96, 1728, false>(A, we1, Eo, t * 128, tid, Bs);
        } else {
            int r = bid - SEG_L1; int n = r / 54, t = r - n * 54;
            proj_body<48, 6912, true>(f0 + (long)n * 48 * 6912, we0,
                Ebase + E0_OFF + (long)n * 6912 * 128, t * 128, tid, Bs);
        }
    } else {
        // ---- convT2 transpose+cast ----
        int idx = (bid - SEG_L0) * 256 + tid;
        if (idx < 147456) {
            int o = idx / 1152, kk = idx - o * 1152;
            int k2 = kk >> 7, c = kk & 127;
            convT2[idx] = f2bf_rne(conv_w[o * 1152 + c * 9 + k2]);
        }
    }
}

// ---------------- gather + sampling + mean + blend -> new_query, samp ----------------
// 8 positions/block, 32 lanes/position, 4 channels/lane (float4).
// Sampling offsets computed inline from the SAME query row the blend needs:
// per-lane partial dot + shfl_xor reduce over the 32-lane position group.
__global__ __launch_bounds__(256) void gather_k(
    const unsigned short* __restrict__ Ebase,
    const float* __restrict__ query, const float* __restrict__ key,
    const float* __restrict__ w_off, const float* __restrict__ b_off,
    const float* __restrict__ awbuf,
    const float* __restrict__ be0, const float* __restrict__ be1,
    const float* __restrict__ be2, const float* __restrict__ be3,
    float* __restrict__ nq, float* __restrict__ samp)
{
    const int tid = threadIdx.x;
    const int pos = blockIdx.x * 8 + (tid >> 5);
    if (pos >= NPOS) return;
    const int l32 = tid & 31;
    const int c4  = l32 << 2;
    const int bt1 = pos / 153, q = pos - bt1 * 153;
    const int b  = bt1 / 243, t1 = bt1 - b * 243;
    const int t2 = t1 / 27,  t3 = t1 - t2 * 27;
    const int n  = b * 9 + t2;
    const int p  = q % 17;

    // query row (used for both the offset dot-product and the final blend)
    const long qi = ((long)bt1 * 153 + q) * 128 + c4;
    const float4 qv = *(const float4*)(query + qi);

    // ---- sampling offsets: off_o = tanh(q·w_off[o] + b_off[o]) ----
    float4 w0 = *(const float4*)(w_off + c4);
    float4 w1 = *(const float4*)(w_off + 128 + c4);
    float s0 = qv.x * w0.x + qv.y * w0.y + qv.z * w0.z + qv.w * w0.w;
    float s1 = qv.x * w1.x + qv.y * w1.y + qv.z * w1.z + qv.w * w1.w;
    #pragma unroll
    for (int m = 16; m >= 1; m >>= 1) {
        s0 += __shfl_xor(s0, m);
        s1 += __shfl_xor(s1, m);
    }
    const float aw0 = awbuf[(bt1 * 17 + p) * 2];
    const float aw1 = awbuf[(bt1 * 17 + p) * 2 + 1];
    const float off0 = tanhf(s0 + b_off[0]);
    const float off1 = tanhf(s1 + b_off[1]);
    const long kidx = (((long)n * 27 + t3) * 153 + q) * 2;
    const float gx = key[kidx]     + off0 * aw0;
    const float gy = key[kidx + 1] + off1 * aw1;
    if (l32 == 0) {
        samp[kidx]     = gx;
        samp[kidx + 1] = gy;
    }

    // ---- 4-level bilinear gather of projected features ----
    float ax = 0.f, ay = 0.f, az = 0.f, aww = 0.f;
    const long Eoffs[4] = {E0_OFF, E1_OFF, E2_OFF, E3_OFF};
    const int Hs[4] = {96, 48, 24, 12}, Wd[4] = {72, 36, 18, 9};
    #pragma unroll
    for (int l = 0; l < 4; ++l) {
        const int H = Hs[l], W = Wd[l];
        const unsigned short* E = Ebase + Eoffs[l] + (long)n * H * W * 128 + c4;
        float ix = ((gx + 1.f) * (float)W - 1.f) * 0.5f;
        float iy = ((gy + 1.f) * (float)H - 1.f) * 0.5f;
        float fx0 = floorf(ix), fy0 = floorf(iy);
        int x0 = (int)fx0, y0 = (int)fy0;
        int x1 = x0 + 1, y1 = y0 + 1;
        float wx1 = ix - fx0, wx0 = 1.f - wx1;
        float wy1 = iy - fy0, wy0 = 1.f - wy1;
        float w00 = wy0 * wx0, w01 = wy0 * wx1, w10 = wy1 * wx0, w11 = wy1 * wx1;
        bool vy0 = (unsigned)y0 < (unsigned)H, vy1 = (unsigned)y1 < (unsigned)H;
        bool vx0 = (unsigned)x0 < (unsigned)W, vx1 = (unsigned)x1 < (unsigned)W;
        if (vy0 && vx0) { ushort4 v = *(const ushort4*)(E + ((long)y0 * W + x0) * 128);
            ax = fmaf(w00, bf2f(v.x), ax); ay = fmaf(w00, bf2f(v.y), ay);
            az = fmaf(w00, bf2f(v.z), az); aww = fmaf(w00, bf2f(v.w), aww); }
        if (vy0 && vx1) { ushort4 v = *(const ushort4*)(E + ((long)y0 * W + x1) * 128);
            ax = fmaf(w01, bf2f(v.x), ax); ay = fmaf(w01, bf2f(v.y), ay);
            az = fmaf(w01, bf2f(v.z), az); aww = fmaf(w01, bf2f(v.w), aww); }
        if (vy1 && vx0) { ushort4 v = *(const ushort4*)(E + ((long)y1 * W + x0) * 128);
            ax = fmaf(w10, bf2f(v.x), ax); ay = fmaf(w10, bf2f(v.y), ay);
            az = fmaf(w10, bf2f(v.z), az); aww = fmaf(w10, bf2f(v.w), aww); }
        if (vy1 && vx1) { ushort4 v = *(const ushort4*)(E + ((long)y1 * W + x1) * 128);
            ax = fmaf(w11, bf2f(v.x), ax); ay = fmaf(w11, bf2f(v.y), ay);
            az = fmaf(w11, bf2f(v.z), az); aww = fmaf(w11, bf2f(v.w), aww); }
    }
    float bsx = be0[c4]     + be1[c4]     + be2[c4]     + be3[c4];
    float bsy = be0[c4 + 1] + be1[c4 + 1] + be2[c4 + 1] + be3[c4 + 1];
    float bsz = be0[c4 + 2] + be1[c4 + 2] + be2[c4 + 2] + be3[c4 + 2];
    float bsw = be0[c4 + 3] + be1[c4 + 3] + be2[c4 + 3] + be3[c4 + 3];
    float mx = 0.25f * (ax + bsx), my = 0.25f * (ay + bsy);
    float mz = 0.25f * (az + bsz), mw = 0.25f * (aww + bsw);
    float4 o;
    o.x = 0.1f * mx + 0.9f * qv.x;
    o.y = 0.1f * my + 0.9f * qv.y;
    o.z = 0.1f * mz + 0.9f * qv.z;
    o.w = 0.1f * mw + 0.9f * qv.w;
    *(float4*)(nq + qi) = o;
}

// ---------------- conv GEMM via bf16 MFMA (BK=64) ----------------
// nv[m][o] = sum_kk nq[m*1152+kk] * convT2[o][kk] + conv_b[o]
__global__ __launch_bounds__(256) void conv_mfma_k(
    const float* __restrict__ nq, const unsigned short* __restrict__ convT2,
    const float* __restrict__ conv_b, float* __restrict__ nv)
{
    __shared__ unsigned short As[32][72];   // [m][k] BK=64, pad->72
    __shared__ unsigned short Bs[64][72];   // [n][k]

    const int tid  = threadIdx.x;
    const int lane = tid & 63;
    const int wave = tid >> 6;
    const int wm = (wave & 1) * 16;
    const int wn = (wave >> 1) * 32;
    const int m0 = blockIdx.x * 32;
    const int n0 = blockIdx.y * 64;
    const int l15  = lane & 15;
    const int quad = lane >> 4;

    floatx4 acc[2];
    acc[0] = (floatx4){0.f, 0.f, 0.f, 0.f};
    acc[1] = acc[0];

    const int am = tid >> 3;             // 0..31
    const int ak = (tid & 7) << 3;       // 0,8,..,56
    const int bn = tid >> 2;             // 0..63
    const int bk = (tid & 3) << 4;       // 0,16,32,48

    float4 a0, a1; uint4 bv0, bv1;
    auto fetch = [&](int k0) {
        a0 = (float4){0,0,0,0}; a1 = a0;
        int row = m0 + am;
        if (row < M_CONV) {
            a0 = *(const float4*)(nq + (long)row * 1152 + k0 + ak);
            a1 = *(const float4*)(nq + (long)row * 1152 + k0 + ak + 4);
        }
        bv0 = *(const uint4*)(convT2 + (long)(n0 + bn) * 1152 + k0 + bk);
        bv1 = *(const uint4*)(convT2 + (long)(n0 + bn) * 1152 + k0 + bk + 8);
    };
    fetch(0);

    for (int k0 = 0; k0 < 1152; k0 += 64) {
        unsigned short t[8] = {f2bf_rne(a0.x), f2bf_rne(a0.y), f2bf_rne(a0.z), f2bf_rne(a0.w),
                               f2bf_rne(a1.x), f2bf_rne(a1.y), f2bf_rne(a1.z), f2bf_rne(a1.w)};
        *(uint4*)&As[am][ak] = *(const uint4*)t;
        *(uint4*)&Bs[bn][bk] = bv0;
        *(uint4*)&Bs[bn][bk + 8] = bv1;
        __syncthreads();
        if (k0 + 64 < 1152) fetch(k0 + 64);

        #pragma unroll
        for (int kt = 0; kt < 2; ++kt) {
            short8 af = *(const short8*)&As[wm + l15][kt * 32 + quad * 8];
            #pragma unroll
            for (int nt = 0; nt < 2; ++nt) {
                short8 bf = *(const short8*)&Bs[wn + nt * 16 + l15][kt * 32 + quad * 8];
                acc[nt] = __builtin_amdgcn_mfma_f32_16x16x32_bf16(af, bf, acc[nt], 0, 0, 0);
            }
        }
        __syncthreads();
    }

    #pragma unroll
    for (int nt = 0; nt < 2; ++nt) {
        int col = n0 + wn + nt * 16 + l15;
        float bias = conv_b[col];
        #pragma unroll
        for (int r = 0; r < 4; ++r) {
            int row = m0 + wm + quad * 4 + r;
            if (row < M_CONV)
                nv[(long)row * 128 + col] = acc[nt][r] + bias;
        }
    }
}

extern "C" void kernel_launch(void* const* d_in, const int* in_sizes, int n_in,
                              void* d_out, int out_size, void* d_ws, size_t ws_size,
                              hipStream_t stream) {
    const float* f0     = (const float*)d_in[0];
    const float* f1     = (const float*)d_in[1];
    const float* f2     = (const float*)d_in[2];
    const float* f3     = (const float*)d_in[3];
    const float* query  = (const float*)d_in[4];
    const float* key    = (const float*)d_in[5];
    const float* value  = (const float*)d_in[6];
    const float* w_off  = (const float*)d_in[7];
    const float* b_off  = (const float*)d_in[8];
    const float* w_attn = (const float*)d_in[9];
    const float* b_attn = (const float*)d_in[10];
    const float* we0    = (const float*)d_in[11];
    const float* be0    = (const float*)d_in[12];
    const float* we1    = (const float*)d_in[13];
    const float* be1    = (const float*)d_in[14];
    const float* we2    = (const float*)d_in[15];
    const float* be2    = (const float*)d_in[16];
    const float* we3    = (const float*)d_in[17];
    const float* be3    = (const float*)d_in[18];
    const float* conv_w = (const float*)d_in[19];
    const float* conv_b = (const float*)d_in[20];

    float* out  = (float*)d_out;
    float* nq   = out;                       // new_query
    float* nv   = out + NQ_SIZE;             // new_value
    float* samp = out + NQ_SIZE + NV_SIZE;   // sampling_positions

    // ws layout: E maps (bf16, 21,150,720) | convT2 (bf16, 147,456)
    unsigned short* Ebase  = (unsigned short*)d_ws;
    unsigned short* convT2 = Ebase + E_END;
    // attention-weight table (486*17*2 floats = 66KB) lives in the nv region;
    // conv_mfma_k overwrites nv LAST, after gather_k has consumed awbuf.
    float* awbuf = nv;

    // 1. fused prep: aw table + projections (MFMA, A-preload) + convT2
    prep_k<<<PREP_GRID, 256, 0, stream>>>(
        f0, f1, f2, f3, we0, we1, we2, we3, conv_w, convT2,
        value, w_attn, b_attn, awbuf, Ebase);

    // 2. gather + inline sampling + mean + blend -> new_query, samp (9295 blocks)
    gather_k<<<(NPOS + 7) / 8, 256, 0, stream>>>(
        Ebase, query, key, w_off, b_off, awbuf, be0, be1, be2, be3, nq, samp);

    // 3. new_value GEMM via MFMA: M=8262, K=1152, N=128, BK=64 (518 blocks)
    conv_mfma_k<<<dim3(259, 2), 256, 0, stream>>>(nq, convT2, conv_b, nv);
}

// Round 4
// 217.181 us; speedup vs baseline: 1.1204x; 1.0717x over previous
//
#include <hip/hip_runtime.h>
#include <hip/hip_bf16.h>

// ---------------- problem constants ----------------
// B=2 T2=9 T3=27 T1=243 P=17 K2=9 C=128
// CH = {48,96,192,384}, HW = {(96,72),(48,36),(24,18),(12,9)}, N=18
static constexpr int NQ_SIZE = 9517824;
static constexpr int NV_SIZE = 1057536;
static constexpr int NPOS    = 74358;   // 486*153 sampling points
static constexpr int M_CONV  = 8262;    // 2*243*17 rows of the conv GEMM

// E-map (projected feature, bf16, channels-last [n,h,w,128]) element offsets in ws
static constexpr long E0_OFF = 0;
static constexpr long E1_OFF = 15925248;            // 18*96*72*128
static constexpr long E2_OFF = E1_OFF + 3981312;    // 18*48*36*128
static constexpr long E3_OFF = E2_OFF + 995328;     // 18*24*18*128
static constexpr long E_END  = E3_OFF + 248832;     // 18*12*9*128  -> 21,150,720 elems

// prep kernel block-range segmentation (heavy GEMM segments first)
static constexpr int SEG_L3 = 18;             // M=108  K=384, 1 tile  x 18
static constexpr int SEG_L2 = SEG_L3 + 72;    // M=432  K=192, 4 tiles x 18
static constexpr int SEG_L1 = SEG_L2 + 252;   // M=1728 K=96, 14 tiles x 18
static constexpr int SEG_L0 = SEG_L1 + 972;   // M=6912 K=48, 54 tiles x 18
static constexpr int SEG_AW = SEG_L0 + 65;    // attention weights: 16524 threads
static constexpr int SEG_CT = SEG_AW + 576;   // convT2: 147456/256
static constexpr int PREP_GRID = SEG_CT + 1;  // +1 block: bias-sum table

typedef __attribute__((ext_vector_type(8))) short short8;   // 8 bf16 (4 VGPRs)
typedef __attribute__((ext_vector_type(4))) float floatx4;

__device__ __forceinline__ float bf2f(unsigned short u) {
    union { unsigned int i; float f; } v; v.i = ((unsigned)u) << 16; return v.f;
}
__device__ __forceinline__ unsigned short f2bf_rne(float f) {
    union { float f; unsigned int i; } v; v.f = f;
    unsigned int u = v.i;
    u += 0x7fffu + ((u >> 16) & 1u);
    return (unsigned short)(u >> 16);
}
__device__ __forceinline__ short8 pack8(const float* t) {
    union { unsigned short u[8]; short8 s; } r;
    #pragma unroll
    for (int i = 0; i < 8; ++i) r.u[i] = f2bf_rne(t[i]);
    return r.s;
}

// ---------------- projection GEMM body ----------------
// E[m, o] = sum_k A[k, m] * W[o, k]   (A = f_l slab, column-major in m; W = we_l)
// Tile M=128 x N=128 per block, 4 waves each owning 32 rows (2 A-frags).
// B staged to LDS per <=96-wide K-chunk (1 barrier/chunk), A loaded JIT per
// k-tile (low VGPR -> 4 waves/SIMD). Epilogue: acc -> LDS bf16 tile -> wide
// coalesced uint4 stores (replaces 64x 2B scalar stores per thread).
template<int K, int M, bool FULLM>
__device__ __forceinline__ void proj_body(
    const float* __restrict__ A, const float* __restrict__ W,
    unsigned short* __restrict__ Eo, int m0, int tid,
    unsigned short* __restrict__ shbuf)
{
    constexpr int KC      = (K < 96) ? K : 96;     // chunk width
    constexpr int KCPAD   = (KC + 31) & ~31;       // padded to mult of 32
    constexpr int KT      = KCPAD / 32;            // k-tiles per chunk
    constexpr int NCH     = K / KC;                // chunks
    constexpr bool NEEDPAD = (KCPAD != KC);        // only K=48

    unsigned short (*Bs)[104] = (unsigned short (*)[104])shbuf;

    const int lane = tid & 63;
    const int wave = tid >> 6;
    const int l15  = lane & 15;
    const int quad = lane >> 4;
    const int mg0  = m0 + wave * 32 + l15;
    const int mg1  = mg0 + 16;
    const bool v0  = FULLM || (mg0 < M);
    const bool v1  = FULLM || (mg1 < M);

    floatx4 acc[2][8];
    #pragma unroll
    for (int f = 0; f < 2; ++f)
        #pragma unroll
        for (int nt = 0; nt < 8; ++nt) acc[f][nt] = (floatx4){0.f, 0.f, 0.f, 0.f};

    // B staging split: thread -> o = tid>>1 (0..127), k-half = (tid&1)*KCPAD/2
    const int so  = tid >> 1;
    const int skb = (tid & 1) * (KCPAD / 2);

    #pragma unroll 1
    for (int ch = 0; ch < NCH; ++ch) {
        const int kc = ch * KC;
        if (ch) __syncthreads();     // previous chunk's readers done

        // ---- stage B chunk (fp32 global -> bf16 LDS), zero-pad beyond KC ----
        {
            const float* wp = W + (long)so * K + kc + skb;
            #pragma unroll
            for (int j = 0; j < KCPAD / 2; j += 8) {
                float t8[8];
                #pragma unroll
                for (int i = 0; i < 8; ++i)
                    t8[i] = (!NEEDPAD || (skb + j + i < KC)) ? wp[j + i] : 0.f;
                unsigned short u[8];
                #pragma unroll
                for (int i = 0; i < 8; ++i) u[i] = f2bf_rne(t8[i]);
                *(uint4*)&Bs[so][skb + j] = *(const uint4*)u;
            }
        }
        __syncthreads();

        // ---- barrier-free k-loop over this chunk (JIT A loads) ----
        #pragma unroll
        for (int kt = 0; kt < KT; ++kt) {
            const int kg = kc + kt * 32 + quad * 8;
            const float* ap = A + (long)kg * M + mg0;
            float a0[8], a1[8];
            if (FULLM && (!NEEDPAD || (kg + 8 <= K))) {
                #pragma unroll
                for (int j = 0; j < 8; ++j) {
                    a0[j] = ap[(long)j * M];
                    a1[j] = ap[(long)j * M + 16];
                }
            } else {
                #pragma unroll
                for (int j = 0; j < 8; ++j) {
                    a0[j] = 0.f; a1[j] = 0.f;
                    if (kg + j < K) {
                        if (v0) a0[j] = ap[(long)j * M];
                        if (v1) a1[j] = ap[(long)j * M + 16];
                    }
                }
            }
            short8 af0 = pack8(a0);
            short8 af1 = pack8(a1);
            #pragma unroll
            for (int nt = 0; nt < 8; ++nt) {
                short8 bf = *(const short8*)&Bs[nt * 16 + l15][kt * 32 + quad * 8];
                acc[0][nt] = __builtin_amdgcn_mfma_f32_16x16x32_bf16(af0, bf, acc[0][nt], 0, 0, 0);
                acc[1][nt] = __builtin_amdgcn_mfma_f32_16x16x32_bf16(af1, bf, acc[1][nt], 0, 0, 0);
            }
        }
    }

    // ---- epilogue: stage bf16 tile in LDS, then wide coalesced stores ----
    __syncthreads();    // all waves done reading Bs
    #pragma unroll
    for (int f = 0; f < 2; ++f) {
        #pragma unroll
        for (int nt = 0; nt < 8; ++nt) {
            #pragma unroll
            for (int r = 0; r < 4; ++r) {
                int row = wave * 32 + f * 16 + quad * 4 + r;
                shbuf[row * 128 + nt * 16 + l15] = f2bf_rne(acc[f][nt][r]);
            }
        }
    }
    __syncthreads();
    const uint4* sb4 = (const uint4*)shbuf;
    uint4* eo4 = (uint4*)(Eo + (long)m0 * 128);
    #pragma unroll
    for (int j = 0; j < 8; ++j) {
        int off16 = wave * 512 + j * 64 + lane;     // uint4 index, 16 per row
        if (FULLM || (m0 + (off16 >> 4) < M))
            eo4[off16] = sb4[off16];
    }
}

// ---------------- fused prep kernel ----------------
__global__ __launch_bounds__(256) void prep_k(
    const float* __restrict__ f0, const float* __restrict__ f1,
    const float* __restrict__ f2, const float* __restrict__ f3,
    const float* __restrict__ we0, const float* __restrict__ we1,
    const float* __restrict__ we2, const float* __restrict__ we3,
    const float* __restrict__ conv_w, unsigned short* __restrict__ convT2,
    const float* __restrict__ value,
    const float* __restrict__ w_attn, const float* __restrict__ b_attn,
    const float* __restrict__ be0, const float* __restrict__ be1,
    const float* __restrict__ be2, const float* __restrict__ be3,
    float* __restrict__ awbuf, float* __restrict__ besum,
    unsigned short* __restrict__ Ebase)
{
    __shared__ unsigned short shbuf[128 * 128];   // 32KB: B-stage / epilogue tile
    const int bid = blockIdx.x;
    const int tid = threadIdx.x;

    if (bid < SEG_L0) {
        if (bid < SEG_L3) {
            int n = bid;
            proj_body<384, 108, false>(f3 + (long)n * 384 * 108, we3,
                Ebase + E3_OFF + (long)n * 108 * 128, 0, tid, shbuf);
        } else if (bid < SEG_L2) {
            int r = bid - SEG_L3; int n = r >> 2, t = r & 3;
            const float* A = f2 + (long)n * 192 * 432;
            unsigned short* Eo = Ebase + E2_OFF + (long)n * 432 * 128;
            if (t < 3) proj_body<192, 432, true >(A, we2, Eo, t * 128, tid, shbuf);
            else       proj_body<192, 432, false>(A, we2, Eo, t * 128, tid, shbuf);
        } else if (bid < SEG_L1) {
            int r = bid - SEG_L2; int n = r / 14, t = r - n * 14;
            const float* A = f1 + (long)n * 96 * 1728;
            unsigned short* Eo = Ebase + E1_OFF + (long)n * 1728 * 128;
            if (t < 13) proj_body<96, 1728, true >(A, we1, Eo, t * 128, tid, shbuf);
            else        proj_body<96, 1728, false>(A, we1, Eo, t * 128, tid, shbuf);
        } else {
            int r = bid - SEG_L1; int n = r / 54, t = r - n * 54;
            proj_body<48, 6912, true>(f0 + (long)n * 48 * 6912, we0,
                Ebase + E0_OFF + (long)n * 6912 * 128, t * 128, tid, shbuf);
        }
    } else if (bid < SEG_AW) {
        // ---- attention weights: 2 threads per (bt1,p) row, shfl partner swap ----
        int t = (bid - SEG_L0) * 256 + tid;
        if (t < 16524) {
            int rp = t >> 1, o = t & 1;
            const float* vrow = value + (long)rp * 128;
            const float* wrow = w_attn + o * 128;
            float s = 0.f;
            for (int c = 0; c < 128; c += 4) {
                float4 v = *(const float4*)(vrow + c);
                float4 w = *(const float4*)(wrow + c);
                s += v.x * w.x + v.y * w.y + v.z * w.z + v.w * w.w;
            }
            s += b_attn[o];
            float so = __shfl_xor(s, 1);
            float m = fmaxf(s, so);
            float e = __expf(s - m), eo = __expf(so - m);
            awbuf[t] = e / (e + eo);
        }
    } else if (bid < SEG_CT) {
        // ---- convT2 transpose+cast ----
        int idx = (bid - SEG_AW) * 256 + tid;
        if (idx < 147456) {
            int o = idx / 1152, kk = idx - o * 1152;
            int k2 = kk >> 7, c = kk & 127;
            convT2[idx] = f2bf_rne(conv_w[o * 1152 + c * 9 + k2]);
        }
    } else {
        // ---- bias-sum table: besum[c] = be0+be1+be2+be3 ----
        if (tid < 128)
            besum[tid] = be0[tid] + be1[tid] + be2[tid] + be3[tid];
    }
}

// ---------------- gather + sampling + mean + blend -> new_query, samp ----------------
// 16 lanes/position, 8 channels/lane (ushort8 16B E loads). Branchless corner
// handling: clamped coords + zeroed weights, so all 16 loads always issue.
// XCD-aware block swizzle (4648 = 8 x 581): consecutive logical blocks share
// the same n E-slab -> per-XCD L2 locality.
__global__ __launch_bounds__(256) void gather_k(
    const unsigned short* __restrict__ Ebase,
    const float* __restrict__ query, const float* __restrict__ key,
    const float* __restrict__ w_off, const float* __restrict__ b_off,
    const float* __restrict__ awbuf, const float* __restrict__ besum,
    float* __restrict__ nq, float* __restrict__ samp)
{
    const int tid = threadIdx.x;
    const int li  = (blockIdx.x & 7) * 581 + (blockIdx.x >> 3);   // XCD swizzle
    const int pos = li * 16 + (tid >> 4);
    if (pos >= NPOS) return;
    const int l16 = tid & 15;
    const int c8  = l16 << 3;

    const int bt1 = pos / 153, q = pos - bt1 * 153;
    const int b  = bt1 / 243, t1 = bt1 - b * 243;
    const int t2 = t1 / 27,  t3 = t1 - t2 * 27;
    const int n  = b * 9 + t2;
    const int p  = q % 17;

    // query row (used for both the offset dot-product and the final blend)
    const long qi = (long)pos * 128 + c8;
    const float4 qv0 = *(const float4*)(query + qi);
    const float4 qv1 = *(const float4*)(query + qi + 4);

    // ---- sampling offsets: off_o = tanh(q . w_off[o] + b_off[o]) ----
    float4 w0a = *(const float4*)(w_off + c8);
    float4 w0b = *(const float4*)(w_off + c8 + 4);
    float4 w1a = *(const float4*)(w_off + 128 + c8);
    float4 w1b = *(const float4*)(w_off + 128 + c8 + 4);
    float s0 = qv0.x * w0a.x + qv0.y * w0a.y + qv0.z * w0a.z + qv0.w * w0a.w
             + qv1.x * w0b.x + qv1.y * w0b.y + qv1.z * w0b.z + qv1.w * w0b.w;
    float s1 = qv0.x * w1a.x + qv0.y * w1a.y + qv0.z * w1a.z + qv0.w * w1a.w
             + qv1.x * w1b.x + qv1.y * w1b.y + qv1.z * w1b.z + qv1.w * w1b.w;
    #pragma unroll
    for (int m = 8; m >= 1; m >>= 1) {
        s0 += __shfl_xor(s0, m);
        s1 += __shfl_xor(s1, m);
    }
    const float aw0 = awbuf[(bt1 * 17 + p) * 2];
    const float aw1 = awbuf[(bt1 * 17 + p) * 2 + 1];
    const float off0 = tanhf(s0 + b_off[0]);
    const float off1 = tanhf(s1 + b_off[1]);
    const long kidx = (((long)n * 27 + t3) * 153 + q) * 2;
    const float gx = key[kidx]     + off0 * aw0;
    const float gy = key[kidx + 1] + off1 * aw1;
    if (l16 == 0) *(float2*)(samp + kidx) = (float2){gx, gy};

    // ---- 4-level bilinear gather (branchless, clamped + zero-weight) ----
    float acc[8];
    #pragma unroll
    for (int j = 0; j < 8; ++j) acc[j] = 0.f;
    const long Eoffs[4] = {E0_OFF, E1_OFF, E2_OFF, E3_OFF};
    const int Hs[4] = {96, 48, 24, 12}, Wd[4] = {72, 36, 18, 9};
    #pragma unroll
    for (int l = 0; l < 4; ++l) {
        const int H = Hs[l], W = Wd[l];
        const unsigned short* E = Ebase + Eoffs[l] + (long)n * H * W * 128 + c8;
        float ix = ((gx + 1.f) * (float)W - 1.f) * 0.5f;
        float iy = ((gy + 1.f) * (float)H - 1.f) * 0.5f;
        float fx0 = floorf(ix), fy0 = floorf(iy);
        int x0 = (int)fx0, y0 = (int)fy0;
        int x1 = x0 + 1, y1 = y0 + 1;
        float wx1 = ix - fx0, wx0 = 1.f - wx1;
        float wy1 = iy - fy0, wy0 = 1.f - wy1;
        bool vy0 = (unsigned)y0 < (unsigned)H, vy1 = (unsigned)y1 < (unsigned)H;
        bool vx0 = (unsigned)x0 < (unsigned)W, vx1 = (unsigned)x1 < (unsigned)W;
        float w00 = (vy0 && vx0) ? wy0 * wx0 : 0.f;
        float w01 = (vy0 && vx1) ? wy0 * wx1 : 0.f;
        float w10 = (vy1 && vx0) ? wy1 * wx0 : 0.f;
        float w11 = (vy1 && vx1) ? wy1 * wx1 : 0.f;
        int yc0 = min(max(y0, 0), H - 1), yc1 = min(max(y1, 0), H - 1);
        int xc0 = min(max(x0, 0), W - 1), xc1 = min(max(x1, 0), W - 1);
        short8 v00 = *(const short8*)(E + ((long)yc0 * W + xc0) * 128);
        short8 v01 = *(const short8*)(E + ((long)yc0 * W + xc1) * 128);
        short8 v10 = *(const short8*)(E + ((long)yc1 * W + xc0) * 128);
        short8 v11 = *(const short8*)(E + ((long)yc1 * W + xc1) * 128);
        #pragma unroll
        for (int j = 0; j < 8; ++j) {
            float a = acc[j];
            a = fmaf(w00, bf2f((unsigned short)v00[j]), a);
            a = fmaf(w01, bf2f((unsigned short)v01[j]), a);
            a = fmaf(w10, bf2f((unsigned short)v10[j]), a);
            a = fmaf(w11, bf2f((unsigned short)v11[j]), a);
            acc[j] = a;
        }
    }
    const float4 bs0 = *(const float4*)(besum + c8);
    const float4 bs1 = *(const float4*)(besum + c8 + 4);
    float4 o0, o1;
    o0.x = 0.1f * (0.25f * (acc[0] + bs0.x)) + 0.9f * qv0.x;
    o0.y = 0.1f * (0.25f * (acc[1] + bs0.y)) + 0.9f * qv0.y;
    o0.z = 0.1f * (0.25f * (acc[2] + bs0.z)) + 0.9f * qv0.z;
    o0.w = 0.1f * (0.25f * (acc[3] + bs0.w)) + 0.9f * qv0.w;
    o1.x = 0.1f * (0.25f * (acc[4] + bs1.x)) + 0.9f * qv1.x;
    o1.y = 0.1f * (0.25f * (acc[5] + bs1.y)) + 0.9f * qv1.y;
    o1.z = 0.1f * (0.25f * (acc[6] + bs1.z)) + 0.9f * qv1.z;
    o1.w = 0.1f * (0.25f * (acc[7] + bs1.w)) + 0.9f * qv1.w;
    *(float4*)(nq + qi)     = o0;
    *(float4*)(nq + qi + 4) = o1;
}

// ---------------- conv GEMM via bf16 MFMA (BK=64) ----------------
// nv[m][o] = sum_kk nq[m*1152+kk] * convT2[o][kk] + conv_b[o]
__global__ __launch_bounds__(256) void conv_mfma_k(
    const float* __restrict__ nq, const unsigned short* __restrict__ convT2,
    const float* __restrict__ conv_b, float* __restrict__ nv)
{
    __shared__ unsigned short As[32][72];   // [m][k] BK=64, pad->72
    __shared__ unsigned short Bs[64][72];   // [n][k]

    const int tid  = threadIdx.x;
    const int lane = tid & 63;
    const int wave = tid >> 6;
    const int wm = (wave & 1) * 16;
    const int wn = (wave >> 1) * 32;
    const int m0 = blockIdx.x * 32;
    const int n0 = blockIdx.y * 64;
    const int l15  = lane & 15;
    const int quad = lane >> 4;

    floatx4 acc[2];
    acc[0] = (floatx4){0.f, 0.f, 0.f, 0.f};
    acc[1] = acc[0];

    const int am = tid >> 3;             // 0..31
    const int ak = (tid & 7) << 3;       // 0,8,..,56
    const int bn = tid >> 2;             // 0..63
    const int bk = (tid & 3) << 4;       // 0,16,32,48

    float4 a0, a1; uint4 bv0, bv1;
    auto fetch = [&](int k0) {
        a0 = (float4){0,0,0,0}; a1 = a0;
        int row = m0 + am;
        if (row < M_CONV) {
            a0 = *(const float4*)(nq + (long)row * 1152 + k0 + ak);
            a1 = *(const float4*)(nq + (long)row * 1152 + k0 + ak + 4);
        }
        bv0 = *(const uint4*)(convT2 + (long)(n0 + bn) * 1152 + k0 + bk);
        bv1 = *(const uint4*)(convT2 + (long)(n0 + bn) * 1152 + k0 + bk + 8);
    };
    fetch(0);

    for (int k0 = 0; k0 < 1152; k0 += 64) {
        unsigned short t[8] = {f2bf_rne(a0.x), f2bf_rne(a0.y), f2bf_rne(a0.z), f2bf_rne(a0.w),
                               f2bf_rne(a1.x), f2bf_rne(a1.y), f2bf_rne(a1.z), f2bf_rne(a1.w)};
        *(uint4*)&As[am][ak] = *(const uint4*)t;
        *(uint4*)&Bs[bn][bk] = bv0;
        *(uint4*)&Bs[bn][bk + 8] = bv1;
        __syncthreads();
        if (k0 + 64 < 1152) fetch(k0 + 64);

        #pragma unroll
        for (int kt = 0; kt < 2; ++kt) {
            short8 af = *(const short8*)&As[wm + l15][kt * 32 + quad * 8];
            #pragma unroll
            for (int nt = 0; nt < 2; ++nt) {
                short8 bf = *(const short8*)&Bs[wn + nt * 16 + l15][kt * 32 + quad * 8];
                acc[nt] = __builtin_amdgcn_mfma_f32_16x16x32_bf16(af, bf, acc[nt], 0, 0, 0);
            }
        }
        __syncthreads();
    }

    #pragma unroll
    for (int nt = 0; nt < 2; ++nt) {
        int col = n0 + wn + nt * 16 + l15;
        float bias = conv_b[col];
        #pragma unroll
        for (int r = 0; r < 4; ++r) {
            int row = m0 + wm + quad * 4 + r;
            if (row < M_CONV)
                nv[(long)row * 128 + col] = acc[nt][r] + bias;
        }
    }
}

extern "C" void kernel_launch(void* const* d_in, const int* in_sizes, int n_in,
                              void* d_out, int out_size, void* d_ws, size_t ws_size,
                              hipStream_t stream) {
    const float* f0     = (const float*)d_in[0];
    const float* f1     = (const float*)d_in[1];
    const float* f2     = (const float*)d_in[2];
    const float* f3     = (const float*)d_in[3];
    const float* query  = (const float*)d_in[4];
    const float* key    = (const float*)d_in[5];
    const float* value  = (const float*)d_in[6];
    const float* w_off  = (const float*)d_in[7];
    const float* b_off  = (const float*)d_in[8];
    const float* w_attn = (const float*)d_in[9];
    const float* b_attn = (const float*)d_in[10];
    const float* we0    = (const float*)d_in[11];
    const float* be0    = (const float*)d_in[12];
    const float* we1    = (const float*)d_in[13];
    const float* be1    = (const float*)d_in[14];
    const float* we2    = (const float*)d_in[15];
    const float* be2    = (const float*)d_in[16];
    const float* we3    = (const float*)d_in[17];
    const float* be3    = (const float*)d_in[18];
    const float* conv_w = (const float*)d_in[19];
    const float* conv_b = (const float*)d_in[20];

    float* out  = (float*)d_out;
    float* nq   = out;                       // new_query
    float* nv   = out + NQ_SIZE;             // new_value
    float* samp = out + NQ_SIZE + NV_SIZE;   // sampling_positions

    // ws layout: E maps (bf16, 21,150,720) | convT2 (bf16, 147,456)
    unsigned short* Ebase  = (unsigned short*)d_ws;
    unsigned short* convT2 = Ebase + E_END;
    // scratch tables live in the nv output region; conv_mfma_k overwrites nv
    // LAST, after gather_k has consumed them.
    float* awbuf = nv;                 // 486*17*2 floats
    float* besum = nv + 16524;         // 128 floats

    // 1. fused prep: projections (MFMA, JIT-A, LDS epilogue) + aw + convT2 + besum
    prep_k<<<PREP_GRID, 256, 0, stream>>>(
        f0, f1, f2, f3, we0, we1, we2, we3, conv_w, convT2,
        value, w_attn, b_attn, be0, be1, be2, be3, awbuf, besum, Ebase);

    // 2. gather + inline sampling + mean + blend -> new_query, samp (4648 blocks)
    gather_k<<<4648, 256, 0, stream>>>(
        Ebase, query, key, w_off, b_off, awbuf, besum, nq, samp);

    // 3. new_value GEMM via MFMA: M=8262, K=1152, N=128, BK=64 (518 blocks)
    conv_mfma_k<<<dim3(259, 2), 256, 0, stream>>>(nq, convT2, conv_b, nv);
}

// Round 5
// 215.677 us; speedup vs baseline: 1.1282x; 1.0070x over previous
//
#include <hip/hip_runtime.h>
#include <hip/hip_bf16.h>

// ---------------- problem constants ----------------
// B=2 T2=9 T3=27 T1=243 P=17 K2=9 C=128
// CH = {48,96,192,384}, HW = {(96,72),(48,36),(24,18),(12,9)}, N=18
static constexpr int NQ_SIZE = 9517824;
static constexpr int NV_SIZE = 1057536;
static constexpr int NPOS    = 74358;   // 486*153 sampling points (even!)
static constexpr int M_CONV  = 8262;    // 2*243*17 rows of the conv GEMM

// E-map (projected feature, bf16, channels-last [n,h,w,128]) element offsets in ws
static constexpr long E0_OFF = 0;
static constexpr long E1_OFF = 15925248;            // 18*96*72*128
static constexpr long E2_OFF = E1_OFF + 3981312;    // 18*48*36*128
static constexpr long E3_OFF = E2_OFF + 995328;     // 18*24*18*128
static constexpr long E_END  = E3_OFF + 248832;     // 18*12*9*128  -> 21,150,720 elems

// prep kernel block-range segmentation (heavy GEMM segments first)
static constexpr int SEG_L3 = 18;             // M=108  K=384, 1 tile  x 18
static constexpr int SEG_L2 = SEG_L3 + 72;    // M=432  K=192, 4 tiles x 18
static constexpr int SEG_L1 = SEG_L2 + 252;   // M=1728 K=96, 14 tiles x 18
static constexpr int SEG_L0 = SEG_L1 + 972;   // M=6912 K=48, 54 tiles x 18
static constexpr int SEG_AW = SEG_L0 + 65;    // attention weights: 16524 threads
static constexpr int SEG_CT = SEG_AW + 576;   // convT2: 147456/256
static constexpr int PREP_GRID = SEG_CT + 1;  // +1 block: bias-sum table

typedef __attribute__((ext_vector_type(8))) short short8;   // 8 bf16 (4 VGPRs)
typedef __attribute__((ext_vector_type(4))) float floatx4;

__device__ __forceinline__ float bf2f(unsigned short u) {
    union { unsigned int i; float f; } v; v.i = ((unsigned)u) << 16; return v.f;
}
__device__ __forceinline__ unsigned short f2bf_rne(float f) {
    union { float f; unsigned int i; } v; v.f = f;
    unsigned int u = v.i;
    u += 0x7fffu + ((u >> 16) & 1u);
    return (unsigned short)(u >> 16);
}
__device__ __forceinline__ short8 pack8(const float* t) {
    union { unsigned short u[8]; short8 s; } r;
    #pragma unroll
    for (int i = 0; i < 8; ++i) r.u[i] = f2bf_rne(t[i]);
    return r.s;
}

// ---------------- projection GEMM body ----------------
// E[m, o] = sum_k A[k, m] * W[o, k]   (A = f_l slab, column-major in m; W = we_l)
// Tile M=128 x N=128 per block, 4 waves each owning 32 rows (2 A-frags).
// B staged to LDS per <=96-wide K-chunk (1 barrier/chunk), A loaded JIT per
// k-tile (low VGPR -> 4 waves/SIMD). Epilogue: acc -> LDS bf16 tile -> wide
// coalesced uint4 stores (replaces 64x 2B scalar stores per thread).
template<int K, int M, bool FULLM>
__device__ __forceinline__ void proj_body(
    const float* __restrict__ A, const float* __restrict__ W,
    unsigned short* __restrict__ Eo, int m0, int tid,
    unsigned short* __restrict__ shbuf)
{
    constexpr int KC      = (K < 96) ? K : 96;     // chunk width
    constexpr int KCPAD   = (KC + 31) & ~31;       // padded to mult of 32
    constexpr int KT      = KCPAD / 32;            // k-tiles per chunk
    constexpr int NCH     = K / KC;                // chunks
    constexpr bool NEEDPAD = (KCPAD != KC);        // only K=48

    unsigned short (*Bs)[104] = (unsigned short (*)[104])shbuf;

    const int lane = tid & 63;
    const int wave = tid >> 6;
    const int l15  = lane & 15;
    const int quad = lane >> 4;
    const int mg0  = m0 + wave * 32 + l15;
    const int mg1  = mg0 + 16;
    const bool v0  = FULLM || (mg0 < M);
    const bool v1  = FULLM || (mg1 < M);

    floatx4 acc[2][8];
    #pragma unroll
    for (int f = 0; f < 2; ++f)
        #pragma unroll
        for (int nt = 0; nt < 8; ++nt) acc[f][nt] = (floatx4){0.f, 0.f, 0.f, 0.f};

    // B staging split: thread -> o = tid>>1 (0..127), k-half = (tid&1)*KCPAD/2
    const int so  = tid >> 1;
    const int skb = (tid & 1) * (KCPAD / 2);

    #pragma unroll 1
    for (int ch = 0; ch < NCH; ++ch) {
        const int kc = ch * KC;
        if (ch) __syncthreads();     // previous chunk's readers done

        // ---- stage B chunk (fp32 global -> bf16 LDS), zero-pad beyond KC ----
        {
            const float* wp = W + (long)so * K + kc + skb;
            #pragma unroll
            for (int j = 0; j < KCPAD / 2; j += 8) {
                float t8[8];
                #pragma unroll
                for (int i = 0; i < 8; ++i)
                    t8[i] = (!NEEDPAD || (skb + j + i < KC)) ? wp[j + i] : 0.f;
                unsigned short u[8];
                #pragma unroll
                for (int i = 0; i < 8; ++i) u[i] = f2bf_rne(t8[i]);
                *(uint4*)&Bs[so][skb + j] = *(const uint4*)u;
            }
        }
        __syncthreads();

        // ---- barrier-free k-loop over this chunk (JIT A loads) ----
        #pragma unroll
        for (int kt = 0; kt < KT; ++kt) {
            const int kg = kc + kt * 32 + quad * 8;
            const float* ap = A + (long)kg * M + mg0;
            float a0[8], a1[8];
            if (FULLM && (!NEEDPAD || (kg + 8 <= K))) {
                #pragma unroll
                for (int j = 0; j < 8; ++j) {
                    a0[j] = ap[(long)j * M];
                    a1[j] = ap[(long)j * M + 16];
                }
            } else {
                #pragma unroll
                for (int j = 0; j < 8; ++j) {
                    a0[j] = 0.f; a1[j] = 0.f;
                    if (kg + j < K) {
                        if (v0) a0[j] = ap[(long)j * M];
                        if (v1) a1[j] = ap[(long)j * M + 16];
                    }
                }
            }
            short8 af0 = pack8(a0);
            short8 af1 = pack8(a1);
            #pragma unroll
            for (int nt = 0; nt < 8; ++nt) {
                short8 bf = *(const short8*)&Bs[nt * 16 + l15][kt * 32 + quad * 8];
                acc[0][nt] = __builtin_amdgcn_mfma_f32_16x16x32_bf16(af0, bf, acc[0][nt], 0, 0, 0);
                acc[1][nt] = __builtin_amdgcn_mfma_f32_16x16x32_bf16(af1, bf, acc[1][nt], 0, 0, 0);
            }
        }
    }

    // ---- epilogue: stage bf16 tile in LDS, then wide coalesced stores ----
    __syncthreads();    // all waves done reading Bs
    #pragma unroll
    for (int f = 0; f < 2; ++f) {
        #pragma unroll
        for (int nt = 0; nt < 8; ++nt) {
            #pragma unroll
            for (int r = 0; r < 4; ++r) {
                int row = wave * 32 + f * 16 + quad * 4 + r;
                shbuf[row * 128 + nt * 16 + l15] = f2bf_rne(acc[f][nt][r]);
            }
        }
    }
    __syncthreads();
    const uint4* sb4 = (const uint4*)shbuf;
    uint4* eo4 = (uint4*)(Eo + (long)m0 * 128);
    #pragma unroll
    for (int j = 0; j < 8; ++j) {
        int off16 = wave * 512 + j * 64 + lane;     // uint4 index, 16 per row
        if (FULLM || (m0 + (off16 >> 4) < M))
            eo4[off16] = sb4[off16];
    }
}

// ---------------- fused prep kernel ----------------
__global__ __launch_bounds__(256) void prep_k(
    const float* __restrict__ f0, const float* __restrict__ f1,
    const float* __restrict__ f2, const float* __restrict__ f3,
    const float* __restrict__ we0, const float* __restrict__ we1,
    const float* __restrict__ we2, const float* __restrict__ we3,
    const float* __restrict__ conv_w, unsigned short* __restrict__ convT2,
    const float* __restrict__ value,
    const float* __restrict__ w_attn, const float* __restrict__ b_attn,
    const float* __restrict__ be0, const float* __restrict__ be1,
    const float* __restrict__ be2, const float* __restrict__ be3,
    float* __restrict__ awbuf, float* __restrict__ besum,
    unsigned short* __restrict__ Ebase)
{
    __shared__ unsigned short shbuf[128 * 128];   // 32KB: B-stage / epilogue tile
    const int bid = blockIdx.x;
    const int tid = threadIdx.x;

    if (bid < SEG_L0) {
        if (bid < SEG_L3) {
            int n = bid;
            proj_body<384, 108, false>(f3 + (long)n * 384 * 108, we3,
                Ebase + E3_OFF + (long)n * 108 * 128, 0, tid, shbuf);
        } else if (bid < SEG_L2) {
            int r = bid - SEG_L3; int n = r >> 2, t = r & 3;
            const float* A = f2 + (long)n * 192 * 432;
            unsigned short* Eo = Ebase + E2_OFF + (long)n * 432 * 128;
            if (t < 3) proj_body<192, 432, true >(A, we2, Eo, t * 128, tid, shbuf);
            else       proj_body<192, 432, false>(A, we2, Eo, t * 128, tid, shbuf);
        } else if (bid < SEG_L1) {
            int r = bid - SEG_L2; int n = r / 14, t = r - n * 14;
            const float* A = f1 + (long)n * 96 * 1728;
            unsigned short* Eo = Ebase + E1_OFF + (long)n * 1728 * 128;
            if (t < 13) proj_body<96, 1728, true >(A, we1, Eo, t * 128, tid, shbuf);
            else        proj_body<96, 1728, false>(A, we1, Eo, t * 128, tid, shbuf);
        } else {
            int r = bid - SEG_L1; int n = r / 54, t = r - n * 54;
            proj_body<48, 6912, true>(f0 + (long)n * 48 * 6912, we0,
                Ebase + E0_OFF + (long)n * 6912 * 128, t * 128, tid, shbuf);
        }
    } else if (bid < SEG_AW) {
        // ---- attention weights: 2 threads per (bt1,p) row, shfl partner swap ----
        int t = (bid - SEG_L0) * 256 + tid;
        if (t < 16524) {
            int rp = t >> 1, o = t & 1;
            const float* vrow = value + (long)rp * 128;
            const float* wrow = w_attn + o * 128;
            float s = 0.f;
            for (int c = 0; c < 128; c += 4) {
                float4 v = *(const float4*)(vrow + c);
                float4 w = *(const float4*)(wrow + c);
                s += v.x * w.x + v.y * w.y + v.z * w.z + v.w * w.w;
            }
            s += b_attn[o];
            float so = __shfl_xor(s, 1);
            float m = fmaxf(s, so);
            float e = __expf(s - m), eo = __expf(so - m);
            awbuf[t] = e / (e + eo);
        }
    } else if (bid < SEG_CT) {
        // ---- convT2 transpose+cast ----
        int idx = (bid - SEG_AW) * 256 + tid;
        if (idx < 147456) {
            int o = idx / 1152, kk = idx - o * 1152;
            int k2 = kk >> 7, c = kk & 127;
            convT2[idx] = f2bf_rne(conv_w[o * 1152 + c * 9 + k2]);
        }
    } else {
        // ---- bias-sum table: besum[c] = be0+be1+be2+be3 ----
        if (tid < 128)
            besum[tid] = be0[tid] + be1[tid] + be2[tid] + be3[tid];
    }
}

// ---------------- gather + sampling + mean + blend -> new_query, samp ----------------
// 16 lanes/position-PAIR, 8 channels/lane. Each group handles TWO consecutive
// positions -> two independent dependency chains per thread (2x MLP: 32 E-loads
// in flight). NPOS is even, so a single uniform group guard suffices.
// XCD-aware block swizzle (2328 = 8 x 291).
__global__ __launch_bounds__(256) void gather_k(
    const unsigned short* __restrict__ Ebase,
    const float* __restrict__ query, const float* __restrict__ key,
    const float* __restrict__ w_off, const float* __restrict__ b_off,
    const float* __restrict__ awbuf, const float* __restrict__ besum,
    float* __restrict__ nq, float* __restrict__ samp)
{
    const int tid = threadIdx.x;
    const int li  = (blockIdx.x & 7) * 291 + (blockIdx.x >> 3);   // XCD swizzle
    const int grp = tid >> 4;
    const int l16 = tid & 15;
    const int c8  = l16 << 3;
    const int pA  = li * 32 + grp * 2;
    if (pA >= NPOS) return;          // pA even, NPOS even -> pB=pA+1 also valid
    const int pB  = pA + 1;

    // ---- shared weight rows ----
    const float4 w0a = *(const float4*)(w_off + c8);
    const float4 w0b = *(const float4*)(w_off + c8 + 4);
    const float4 w1a = *(const float4*)(w_off + 128 + c8);
    const float4 w1b = *(const float4*)(w_off + 128 + c8 + 4);

    // ---- query rows (both positions; also used for the final blend) ----
    const long qiA = (long)pA * 128 + c8;
    const long qiB = qiA + 128;
    const float4 qA0 = *(const float4*)(query + qiA);
    const float4 qA1 = *(const float4*)(query + qiA + 4);
    const float4 qB0 = *(const float4*)(query + qiB);
    const float4 qB1 = *(const float4*)(query + qiB + 4);

    // ---- offset dot products, 4 independent shfl reductions interleaved ----
    float sA0 = qA0.x*w0a.x + qA0.y*w0a.y + qA0.z*w0a.z + qA0.w*w0a.w
              + qA1.x*w0b.x + qA1.y*w0b.y + qA1.z*w0b.z + qA1.w*w0b.w;
    float sA1 = qA0.x*w1a.x + qA0.y*w1a.y + qA0.z*w1a.z + qA0.w*w1a.w
              + qA1.x*w1b.x + qA1.y*w1b.y + qA1.z*w1b.z + qA1.w*w1b.w;
    float sB0 = qB0.x*w0a.x + qB0.y*w0a.y + qB0.z*w0a.z + qB0.w*w0a.w
              + qB1.x*w0b.x + qB1.y*w0b.y + qB1.z*w0b.z + qB1.w*w0b.w;
    float sB1 = qB0.x*w1a.x + qB0.y*w1a.y + qB0.z*w1a.z + qB0.w*w1a.w
              + qB1.x*w1b.x + qB1.y*w1b.y + qB1.z*w1b.z + qB1.w*w1b.w;
    #pragma unroll
    for (int m = 8; m >= 1; m >>= 1) {
        sA0 += __shfl_xor(sA0, m); sA1 += __shfl_xor(sA1, m);
        sB0 += __shfl_xor(sB0, m); sB1 += __shfl_xor(sB1, m);
    }

    // ---- position decode + sampling coords ----
    const float bo0 = b_off[0], bo1 = b_off[1];

    const int bt1A = pA / 153, qqA = pA - bt1A * 153;
    const int bAi = bt1A / 243, t1A = bt1A - bAi * 243;
    const int t2A = t1A / 27,  t3A = t1A - t2A * 27;
    const int nA  = bAi * 9 + t2A;
    const int ppA = qqA % 17;
    const long kiA = (((long)nA * 27 + t3A) * 153 + qqA) * 2;
    const float2 kvA = *(const float2*)(key + kiA);
    const float2 awA = *(const float2*)(awbuf + (bt1A * 17 + ppA) * 2);
    const float gxA = kvA.x + tanhf(sA0 + bo0) * awA.x;
    const float gyA = kvA.y + tanhf(sA1 + bo1) * awA.y;

    const int bt1B = pB / 153, qqB = pB - bt1B * 153;
    const int bBi = bt1B / 243, t1B = bt1B - bBi * 243;
    const int t2B = t1B / 27,  t3B = t1B - t2B * 27;
    const int nB  = bBi * 9 + t2B;
    const int ppB = qqB % 17;
    const long kiB = (((long)nB * 27 + t3B) * 153 + qqB) * 2;
    const float2 kvB = *(const float2*)(key + kiB);
    const float2 awB = *(const float2*)(awbuf + (bt1B * 17 + ppB) * 2);
    const float gxB = kvB.x + tanhf(sB0 + bo0) * awB.x;
    const float gyB = kvB.y + tanhf(sB1 + bo1) * awB.y;

    if (l16 == 0) {
        *(float2*)(samp + kiA) = (float2){gxA, gyA};
        *(float2*)(samp + kiB) = (float2){gxB, gyB};
    }

    // ---- 4-level bilinear gather, both positions (branchless, 8 loads/level) ----
    float accA[8], accB[8];
    #pragma unroll
    for (int j = 0; j < 8; ++j) { accA[j] = 0.f; accB[j] = 0.f; }
    const long Eoffs[4] = {E0_OFF, E1_OFF, E2_OFF, E3_OFF};
    const int Hs[4] = {96, 48, 24, 12}, Wd[4] = {72, 36, 18, 9};
    #pragma unroll
    for (int l = 0; l < 4; ++l) {
        const int H = Hs[l], W = Wd[l];
        const unsigned short* ELA = Ebase + Eoffs[l] + (long)nA * H * W * 128 + c8;
        const unsigned short* ELB = Ebase + Eoffs[l] + (long)nB * H * W * 128 + c8;

        // position A coords/weights
        float ixA = ((gxA + 1.f) * (float)W - 1.f) * 0.5f;
        float iyA = ((gyA + 1.f) * (float)H - 1.f) * 0.5f;
        float fxA = floorf(ixA), fyA = floorf(iyA);
        int xA0 = (int)fxA, yA0 = (int)fyA, xA1 = xA0 + 1, yA1 = yA0 + 1;
        float wxA1 = ixA - fxA, wxA0 = 1.f - wxA1;
        float wyA1 = iyA - fyA, wyA0 = 1.f - wyA1;
        bool vyA0 = (unsigned)yA0 < (unsigned)H, vyA1 = (unsigned)yA1 < (unsigned)H;
        bool vxA0 = (unsigned)xA0 < (unsigned)W, vxA1 = (unsigned)xA1 < (unsigned)W;
        float wA00 = (vyA0 && vxA0) ? wyA0 * wxA0 : 0.f;
        float wA01 = (vyA0 && vxA1) ? wyA0 * wxA1 : 0.f;
        float wA10 = (vyA1 && vxA0) ? wyA1 * wxA0 : 0.f;
        float wA11 = (vyA1 && vxA1) ? wyA1 * wxA1 : 0.f;
        int ycA0 = min(max(yA0, 0), H - 1), ycA1 = min(max(yA1, 0), H - 1);
        int xcA0 = min(max(xA0, 0), W - 1), xcA1 = min(max(xA1, 0), W - 1);

        // position B coords/weights
        float ixB = ((gxB + 1.f) * (float)W - 1.f) * 0.5f;
        float iyB = ((gyB + 1.f) * (float)H - 1.f) * 0.5f;
        float fxB = floorf(ixB), fyB = floorf(iyB);
        int xB0 = (int)fxB, yB0 = (int)fyB, xB1 = xB0 + 1, yB1 = yB0 + 1;
        float wxB1 = ixB - fxB, wxB0 = 1.f - wxB1;
        float wyB1 = iyB - fyB, wyB0 = 1.f - wyB1;
        bool vyB0 = (unsigned)yB0 < (unsigned)H, vyB1 = (unsigned)yB1 < (unsigned)H;
        bool vxB0 = (unsigned)xB0 < (unsigned)W, vxB1 = (unsigned)xB1 < (unsigned)W;
        float wB00 = (vyB0 && vxB0) ? wyB0 * wxB0 : 0.f;
        float wB01 = (vyB0 && vxB1) ? wyB0 * wxB1 : 0.f;
        float wB10 = (vyB1 && vxB0) ? wyB1 * wxB0 : 0.f;
        float wB11 = (vyB1 && vxB1) ? wyB1 * wxB1 : 0.f;
        int ycB0 = min(max(yB0, 0), H - 1), ycB1 = min(max(yB1, 0), H - 1);
        int xcB0 = min(max(xB0, 0), W - 1), xcB1 = min(max(xB1, 0), W - 1);

        // 8 independent 16B loads
        short8 vA00 = *(const short8*)(ELA + ((long)ycA0 * W + xcA0) * 128);
        short8 vA01 = *(const short8*)(ELA + ((long)ycA0 * W + xcA1) * 128);
        short8 vA10 = *(const short8*)(ELA + ((long)ycA1 * W + xcA0) * 128);
        short8 vA11 = *(const short8*)(ELA + ((long)ycA1 * W + xcA1) * 128);
        short8 vB00 = *(const short8*)(ELB + ((long)ycB0 * W + xcB0) * 128);
        short8 vB01 = *(const short8*)(ELB + ((long)ycB0 * W + xcB1) * 128);
        short8 vB10 = *(const short8*)(ELB + ((long)ycB1 * W + xcB0) * 128);
        short8 vB11 = *(const short8*)(ELB + ((long)ycB1 * W + xcB1) * 128);

        #pragma unroll
        for (int j = 0; j < 8; ++j) {
            float a = accA[j];
            a = fmaf(wA00, bf2f((unsigned short)vA00[j]), a);
            a = fmaf(wA01, bf2f((unsigned short)vA01[j]), a);
            a = fmaf(wA10, bf2f((unsigned short)vA10[j]), a);
            a = fmaf(wA11, bf2f((unsigned short)vA11[j]), a);
            accA[j] = a;
            float bb = accB[j];
            bb = fmaf(wB00, bf2f((unsigned short)vB00[j]), bb);
            bb = fmaf(wB01, bf2f((unsigned short)vB01[j]), bb);
            bb = fmaf(wB10, bf2f((unsigned short)vB10[j]), bb);
            bb = fmaf(wB11, bf2f((unsigned short)vB11[j]), bb);
            accB[j] = bb;
        }
    }

    // ---- mean + bias + blend, both rows ----
    const float4 bs0 = *(const float4*)(besum + c8);
    const float4 bs1 = *(const float4*)(besum + c8 + 4);
    float4 oA0, oA1, oB0, oB1;
    oA0.x = 0.1f * (0.25f * (accA[0] + bs0.x)) + 0.9f * qA0.x;
    oA0.y = 0.1f * (0.25f * (accA[1] + bs0.y)) + 0.9f * qA0.y;
    oA0.z = 0.1f * (0.25f * (accA[2] + bs0.z)) + 0.9f * qA0.z;
    oA0.w = 0.1f * (0.25f * (accA[3] + bs0.w)) + 0.9f * qA0.w;
    oA1.x = 0.1f * (0.25f * (accA[4] + bs1.x)) + 0.9f * qA1.x;
    oA1.y = 0.1f * (0.25f * (accA[5] + bs1.y)) + 0.9f * qA1.y;
    oA1.z = 0.1f * (0.25f * (accA[6] + bs1.z)) + 0.9f * qA1.z;
    oA1.w = 0.1f * (0.25f * (accA[7] + bs1.w)) + 0.9f * qA1.w;
    oB0.x = 0.1f * (0.25f * (accB[0] + bs0.x)) + 0.9f * qB0.x;
    oB0.y = 0.1f * (0.25f * (accB[1] + bs0.y)) + 0.9f * qB0.y;
    oB0.z = 0.1f * (0.25f * (accB[2] + bs0.z)) + 0.9f * qB0.z;
    oB0.w = 0.1f * (0.25f * (accB[3] + bs0.w)) + 0.9f * qB0.w;
    oB1.x = 0.1f * (0.25f * (accB[4] + bs1.x)) + 0.9f * qB1.x;
    oB1.y = 0.1f * (0.25f * (accB[5] + bs1.y)) + 0.9f * qB1.y;
    oB1.z = 0.1f * (0.25f * (accB[6] + bs1.z)) + 0.9f * qB1.z;
    oB1.w = 0.1f * (0.25f * (accB[7] + bs1.w)) + 0.9f * qB1.w;
    *(float4*)(nq + qiA)     = oA0;
    *(float4*)(nq + qiA + 4) = oA1;
    *(float4*)(nq + qiB)     = oB0;
    *(float4*)(nq + qiB + 4) = oB1;
}

// ---------------- conv GEMM via bf16 MFMA (BK=64) ----------------
// nv[m][o] = sum_kk nq[m*1152+kk] * convT2[o][kk] + conv_b[o]
__global__ __launch_bounds__(256) void conv_mfma_k(
    const float* __restrict__ nq, const unsigned short* __restrict__ convT2,
    const float* __restrict__ conv_b, float* __restrict__ nv)
{
    __shared__ unsigned short As[32][72];   // [m][k] BK=64, pad->72
    __shared__ unsigned short Bs[64][72];   // [n][k]

    const int tid  = threadIdx.x;
    const int lane = tid & 63;
    const int wave = tid >> 6;
    const int wm = (wave & 1) * 16;
    const int wn = (wave >> 1) * 32;
    const int m0 = blockIdx.x * 32;
    const int n0 = blockIdx.y * 64;
    const int l15  = lane & 15;
    const int quad = lane >> 4;

    floatx4 acc[2];
    acc[0] = (floatx4){0.f, 0.f, 0.f, 0.f};
    acc[1] = acc[0];

    const int am = tid >> 3;             // 0..31
    const int ak = (tid & 7) << 3;       // 0,8,..,56
    const int bn = tid >> 2;             // 0..63
    const int bk = (tid & 3) << 4;       // 0,16,32,48

    float4 a0, a1; uint4 bv0, bv1;
    auto fetch = [&](int k0) {
        a0 = (float4){0,0,0,0}; a1 = a0;
        int row = m0 + am;
        if (row < M_CONV) {
            a0 = *(const float4*)(nq + (long)row * 1152 + k0 + ak);
            a1 = *(const float4*)(nq + (long)row * 1152 + k0 + ak + 4);
        }
        bv0 = *(const uint4*)(convT2 + (long)(n0 + bn) * 1152 + k0 + bk);
        bv1 = *(const uint4*)(convT2 + (long)(n0 + bn) * 1152 + k0 + bk + 8);
    };
    fetch(0);

    for (int k0 = 0; k0 < 1152; k0 += 64) {
        unsigned short t[8] = {f2bf_rne(a0.x), f2bf_rne(a0.y), f2bf_rne(a0.z), f2bf_rne(a0.w),
                               f2bf_rne(a1.x), f2bf_rne(a1.y), f2bf_rne(a1.z), f2bf_rne(a1.w)};
        *(uint4*)&As[am][ak] = *(const uint4*)t;
        *(uint4*)&Bs[bn][bk] = bv0;
        *(uint4*)&Bs[bn][bk + 8] = bv1;
        __syncthreads();
        if (k0 + 64 < 1152) fetch(k0 + 64);

        #pragma unroll
        for (int kt = 0; kt < 2; ++kt) {
            short8 af = *(const short8*)&As[wm + l15][kt * 32 + quad * 8];
            #pragma unroll
            for (int nt = 0; nt < 2; ++nt) {
                short8 bf = *(const short8*)&Bs[wn + nt * 16 + l15][kt * 32 + quad * 8];
                acc[nt] = __builtin_amdgcn_mfma_f32_16x16x32_bf16(af, bf, acc[nt], 0, 0, 0);
            }
        }
        __syncthreads();
    }

    #pragma unroll
    for (int nt = 0; nt < 2; ++nt) {
        int col = n0 + wn + nt * 16 + l15;
        float bias = conv_b[col];
        #pragma unroll
        for (int r = 0; r < 4; ++r) {
            int row = m0 + wm + quad * 4 + r;
            if (row < M_CONV)
                nv[(long)row * 128 + col] = acc[nt][r] + bias;
        }
    }
}

extern "C" void kernel_launch(void* const* d_in, const int* in_sizes, int n_in,
                              void* d_out, int out_size, void* d_ws, size_t ws_size,
                              hipStream_t stream) {
    const float* f0     = (const float*)d_in[0];
    const float* f1     = (const float*)d_in[1];
    const float* f2     = (const float*)d_in[2];
    const float* f3     = (const float*)d_in[3];
    const float* query  = (const float*)d_in[4];
    const float* key    = (const float*)d_in[5];
    const float* value  = (const float*)d_in[6];
    const float* w_off  = (const float*)d_in[7];
    const float* b_off  = (const float*)d_in[8];
    const float* w_attn = (const float*)d_in[9];
    const float* b_attn = (const float*)d_in[10];
    const float* we0    = (const float*)d_in[11];
    const float* be0    = (const float*)d_in[12];
    const float* we1    = (const float*)d_in[13];
    const float* be1    = (const float*)d_in[14];
    const float* we2    = (const float*)d_in[15];
    const float* be2    = (const float*)d_in[16];
    const float* we3    = (const float*)d_in[17];
    const float* be3    = (const float*)d_in[18];
    const float* conv_w = (const float*)d_in[19];
    const float* conv_b = (const float*)d_in[20];

    float* out  = (float*)d_out;
    float* nq   = out;                       // new_query
    float* nv   = out + NQ_SIZE;             // new_value
    float* samp = out + NQ_SIZE + NV_SIZE;   // sampling_positions

    // ws layout: E maps (bf16, 21,150,720) | convT2 (bf16, 147,456)
    unsigned short* Ebase  = (unsigned short*)d_ws;
    unsigned short* convT2 = Ebase + E_END;
    // scratch tables live in the nv output region; conv_mfma_k overwrites nv
    // LAST, after gather_k has consumed them.
    float* awbuf = nv;                 // 486*17*2 floats
    float* besum = nv + 16524;         // 128 floats

    // 1. fused prep: projections (MFMA, JIT-A, LDS epilogue) + aw + convT2 + besum
    prep_k<<<PREP_GRID, 256, 0, stream>>>(
        f0, f1, f2, f3, we0, we1, we2, we3, conv_w, convT2,
        value, w_attn, b_attn, be0, be1, be2, be3, awbuf, besum, Ebase);

    // 2. gather (2 positions per 16-lane group) -> new_query, samp (2328 blocks)
    gather_k<<<2328, 256, 0, stream>>>(
        Ebase, query, key, w_off, b_off, awbuf, besum, nq, samp);

    // 3. new_value GEMM via MFMA: M=8262, K=1152, N=128, BK=64 (518 blocks)
    conv_mfma_k<<<dim3(259, 2), 256, 0, stream>>>(nq, convT2, conv_b, nv);
}